// Round 1
// 512.409 us; speedup vs baseline: 1.1057x; 1.1057x over previous
//
#include <hip/hip_runtime.h>
#include <hip/hip_bf16.h>

// LightGCN on MI355X — block-aggregated bucket build + deep-unrolled gather.
//
// Build history: fill with 150k cursors = no contention but 249MB fragmented
// line writebacks (245us); per-edge bucket atomics on 1172 cursors = 3413
// serialized ops/address (723us). This build aggregates per block: LDS
// histogram over 1172 buckets, ONE global atomic per (block,bucket) to
// reserve a run, contiguous run writes that merge in L2. Then per-bucket
// LDS CSR finalize (round-6 bcsr, proven).
// R9: bscatter was latency-bound at 4.4% occupancy (123 blocks x 4 waves).
// Now 1024-thread blocks, CH=16384 -> 245 blocks x 16 waves (~15 waves/CU),
// per-bucket atomic chain 245 (fine), run length 14 pairs (56B, acceptable).
// Gather: one wave/node, 8 lanes/edge uint4, 2KB in flight (round-8, proven).

#ifndef EMB
#define EMB 64
#endif
#define BSHIFT 7                 // 128 nodes per bucket
#define BNODES (1 << BSHIFT)
#define NBMAX 1280               // LDS histogram capacity
#define CCAP 4800                // LDS pair-staging capacity per bucket
#define CH 16384                 // edges per bscatter block
#define STH 1024                 // bscatter threads per block

typedef unsigned int uint;
typedef unsigned short ushort;

static __device__ __forceinline__ ushort f2bf(float f) {
    __hip_bfloat16 b = __float2bfloat16(f);
    return *(ushort*)&b;
}

// u = two packed bf16; accumulate w * {lo,hi} into aL,aH.
static __device__ __forceinline__ void acc2(uint u, float w, float& aL, float& aH) {
    union { uint x; float f; } lo, hi;
    lo.x = u << 16;
    hi.x = u & 0xffff0000u;
    aL = fmaf(w, lo.f, aL);
    aH = fmaf(w, hi.f, aH);
}

// flag = 1 if edge_index is int64 (high words of first 128 entries all zero).
__global__ void lgcn_detect_kernel(const int* __restrict__ ei, int* __restrict__ flag) {
    __shared__ int any_nz;
    if (threadIdx.x == 0) any_nz = 0;
    __syncthreads();
    if (ei[2 * threadIdx.x + 1] != 0) atomicOr(&any_nz, 1);
    __syncthreads();
    if (threadIdx.x == 0) *flag = (any_nz == 0) ? 1 : 0;
}

static __device__ __forceinline__ int load_idx(const int* __restrict__ ei,
                                               long long elem, int is64,
                                               int n_nodes) {
    int v = is64 ? ei[elem << 1] : ei[elem];
    return min(max(v, 0), n_nodes - 1);
}

// ---- build step 1: bucket histogram (LDS-staged) ----
__global__ void lgcn_bhist_kernel(const int* __restrict__ ei,
                                  const int* __restrict__ flag,
                                  int* __restrict__ bcount,
                                  int n_edges, int n_nodes, int NB) {
    __shared__ int h[NBMAX];
    int t = threadIdx.x;
    int is64 = *flag;
    for (int i = t; i < NB; i += 256) h[i] = 0;
    __syncthreads();
    long long base = (long long)blockIdx.x * 4096 + t;
    #pragma unroll
    for (int k = 0; k < 16; ++k) {
        long long e = base + (long long)k * 256;
        if (e < n_edges) {
            int c = load_idx(ei, (long long)n_edges + e, is64, n_nodes);
            atomicAdd(&h[c >> BSHIFT], 1);
        }
    }
    __syncthreads();
    for (int i = t; i < NB; i += 256) {
        int v = h[i];
        if (v) atomicAdd(&bcount[i], v);
    }
}

// ---- build step 2: exclusive scan of bucket counts (single block) ----
__global__ void lgcn_bscan_kernel(const int* __restrict__ bcount,
                                  int* __restrict__ bucketBase,
                                  int* __restrict__ offsets,
                                  int NB, int n_nodes) {
    __shared__ int tsum[256];
    int t = threadIdx.x;
    int K = (NB + 255) / 256;
    int base = t * K;
    int s = 0;
    for (int k = 0; k < K; ++k) {
        int i = base + k;
        if (i < NB) s += bcount[i];
    }
    tsum[t] = s;
    __syncthreads();
    for (int off = 1; off < 256; off <<= 1) {
        int x = (t >= off) ? tsum[t - off] : 0;
        __syncthreads();
        tsum[t] += x;
        __syncthreads();
    }
    int run = tsum[t] - s;
    for (int k = 0; k < K; ++k) {
        int i = base + k;
        if (i < NB) { bucketBase[i] = run; run += bcount[i]; }
    }
    if (t == 255) {
        bucketBase[NB] = tsum[255];
        offsets[n_nodes] = tsum[255];
    }
}

// ---- build step 3: block-aggregated pair scatter ----
// Per block: LDS bucket histogram of its CH edges, one global atomic per
// (block,bucket) to reserve a contiguous run, then write packed pairs.
// 1024 threads x 245 blocks for latency hiding (R9).
__global__ void __launch_bounds__(STH)
lgcn_bscatter2_kernel(const int* __restrict__ ei,
                      const int* __restrict__ flag,
                      const int* __restrict__ bucketBase,
                      int* __restrict__ bcur,
                      uint* __restrict__ pairs,
                      int n_edges, int n_nodes, int NB) {
    __shared__ int lcount[NBMAX];
    __shared__ int lbase[NBMAX];
    int t = threadIdx.x;
    int is64 = *flag;
    long long base = (long long)blockIdx.x * CH;
    for (int i = t; i < NB; i += STH) lcount[i] = 0;
    __syncthreads();
    // pass 1: local histogram
    for (int k = t; k < CH; k += STH) {
        long long e = base + k;
        if (e < n_edges) {
            int c = load_idx(ei, (long long)n_edges + e, is64, n_nodes);
            atomicAdd(&lcount[c >> BSHIFT], 1);
        }
    }
    __syncthreads();
    // reservation: one global atomic per non-empty bucket
    for (int i = t; i < NB; i += STH) {
        int cnt = lcount[i];
        lbase[i] = cnt ? (bucketBase[i] + atomicAdd(&bcur[i], cnt)) : 0;
        lcount[i] = 0;   // reuse as local cursor
    }
    __syncthreads();
    // pass 2: write pairs into reserved runs (contiguous per bucket-run)
    for (int k = t; k < CH; k += STH) {
        long long e = base + k;
        if (e < n_edges) {
            int r = load_idx(ei, e, is64, n_nodes);
            int c = load_idx(ei, (long long)n_edges + e, is64, n_nodes);
            int b = c >> BSHIFT;
            int pos = lbase[b] + atomicAdd(&lcount[b], 1);
            pairs[pos] = ((uint)r << BSHIFT) | (uint)(c & (BNODES - 1));
        }
    }
}

// ---- build step 4: per-bucket CSR finalize (one block per bucket) ----
__global__ void lgcn_bcsr_kernel(const uint* __restrict__ pairs,
                                 const int* __restrict__ bucketBase,
                                 int* __restrict__ offsets,
                                 int* __restrict__ csr_rows,
                                 float* __restrict__ dis,
                                 int n_nodes) {
    __shared__ int deg[BNODES];
    __shared__ int tmp[BNODES];
    __shared__ int loffx[BNODES];
    __shared__ int cur[BNODES];
    __shared__ uint lp[CCAP];
    int b = blockIdx.x;
    int t = threadIdx.x;            // 256 threads
    int nodeStart = b << BSHIFT;
    int base = bucketBase[b];
    int span = bucketBase[b + 1] - base;
    bool fits = (span <= CCAP);
    if (t < BNODES) deg[t] = 0;
    __syncthreads();
    for (int i = t; i < span; i += 256) {
        uint p = pairs[base + i];
        if (fits) lp[i] = p;
        atomicAdd(&deg[p & (BNODES - 1)], 1);
    }
    __syncthreads();
    if (t < BNODES) tmp[t] = deg[t];
    __syncthreads();
    for (int off = 1; off < BNODES; off <<= 1) {
        int x = (t < BNODES && t >= off) ? tmp[t - off] : 0;
        __syncthreads();
        if (t < BNODES) tmp[t] += x;
        __syncthreads();
    }
    if (t < BNODES) {
        int excl = tmp[t] - deg[t];
        loffx[t] = excl;
        cur[t] = 0;
        int node = nodeStart + t;
        if (node < n_nodes) {
            offsets[node] = base + excl;
            dis[node] = (deg[t] > 0) ? rsqrtf((float)deg[t]) : 0.0f;
        }
    }
    __syncthreads();
    for (int i = t; i < span; i += 256) {
        uint p = fits ? lp[i] : pairs[base + i];
        int cl = (int)(p & (BNODES - 1));
        int pos = loffx[cl] + atomicAdd(&cur[cl], 1);
        csr_rows[base + pos] = (int)(p >> BSHIFT);
    }
}

// init: out(total,fp32) = x ; X(bf16) = x
__global__ void lgcn_init_kernel(const float* __restrict__ user_w,
                                 const float* __restrict__ item_w,
                                 float* __restrict__ total,
                                 ushort* __restrict__ xcatb,
                                 int n_user_elems, int n_total_elems) {
    int i = blockIdx.x * blockDim.x + threadIdx.x;
    if (i < n_total_elems) {
        float v = (i < n_user_elems) ? user_w[i] : item_w[i - n_user_elems];
        total[i] = v;
        xcatb[i] = f2bf(v);
    }
}

// gather: one wave per node; 8 lanes per edge (uint4 = 16B per lane);
// one wave-wide load = 8 edges = 1KB; unrolled x2 = 2KB in flight per wave.
template <bool LAST>
__global__ void lgcn_gather_kernel(const int* __restrict__ csr_rows,
                                   const int* __restrict__ offsets,
                                   const float* __restrict__ dis,
                                   const ushort* __restrict__ xin,
                                   ushort* __restrict__ xout,
                                   float* __restrict__ total,
                                   int n_nodes) {
    long long tid = (long long)blockIdx.x * blockDim.x + threadIdx.x;
    int c    = (int)(tid >> 6);
    int lane = threadIdx.x & 63;
    int oct  = lane >> 3;   // edge slot 0..7 within a group
    int o8   = lane & 7;    // which 16B chunk of the 128B row
    if (c >= n_nodes) return;
    int beg = offsets[c];
    int end = offsets[c + 1];
    float dc = dis[c];
    float a[8];
    #pragma unroll
    for (int k = 0; k < 8; ++k) a[k] = 0.0f;

    for (int j = beg; j < end; j += 16) {
        int j0 = j + oct;
        int j1 = j + 8 + oct;
        bool v0 = j0 < end;
        bool v1 = j1 < end;
        int r0 = csr_rows[v0 ? j0 : beg];
        int r1 = csr_rows[v1 ? j1 : beg];
        float w0 = v0 ? dis[r0] : 0.0f;
        float w1 = v1 ? dis[r1] : 0.0f;
        uint4 q0 = *(const uint4*)(xin + (size_t)r0 * EMB + o8 * 8);
        uint4 q1 = *(const uint4*)(xin + (size_t)r1 * EMB + o8 * 8);
        acc2(q0.x, w0, a[0], a[1]);
        acc2(q0.y, w0, a[2], a[3]);
        acc2(q0.z, w0, a[4], a[5]);
        acc2(q0.w, w0, a[6], a[7]);
        acc2(q1.x, w1, a[0], a[1]);
        acc2(q1.y, w1, a[2], a[3]);
        acc2(q1.z, w1, a[4], a[5]);
        acc2(q1.w, w1, a[6], a[7]);
    }

    #pragma unroll
    for (int k = 0; k < 8; ++k) {
        a[k] += __shfl_xor(a[k], 8, 64);
        a[k] += __shfl_xor(a[k], 16, 64);
        a[k] += __shfl_xor(a[k], 32, 64);
    }

    if (oct == 0) {   // lanes 0..7; lane l holds dims [8*l, 8*l+8)
        #pragma unroll
        for (int k = 0; k < 8; ++k) a[k] *= dc;
        size_t fo = (size_t)c * EMB + o8 * 8;
        float4* t0 = (float4*)(total + fo);
        if (!LAST) {
            uint4 s;
            s.x = ((uint)f2bf(a[1]) << 16) | f2bf(a[0]);
            s.y = ((uint)f2bf(a[3]) << 16) | f2bf(a[2]);
            s.z = ((uint)f2bf(a[5]) << 16) | f2bf(a[4]);
            s.w = ((uint)f2bf(a[7]) << 16) | f2bf(a[6]);
            *(uint4*)(xout + fo) = s;
            float4 t = t0[0];
            t.x += a[0]; t.y += a[1]; t.z += a[2]; t.w += a[3];
            t0[0] = t;
            float4 u = t0[1];
            u.x += a[4]; u.y += a[5]; u.z += a[6]; u.w += a[7];
            t0[1] = u;
        } else {
            float4 t = t0[0];
            t.x = (t.x + a[0]) * 0.25f; t.y = (t.y + a[1]) * 0.25f;
            t.z = (t.z + a[2]) * 0.25f; t.w = (t.w + a[3]) * 0.25f;
            t0[0] = t;
            float4 u = t0[1];
            u.x = (u.x + a[4]) * 0.25f; u.y = (u.y + a[5]) * 0.25f;
            u.z = (u.z + a[6]) * 0.25f; u.w = (u.w + a[7]) * 0.25f;
            t0[1] = u;
        }
    }
}

extern "C" void kernel_launch(void* const* d_in, const int* in_sizes, int n_in,
                              void* d_out, int out_size, void* d_ws, size_t ws_size,
                              hipStream_t stream) {
    // ---- role assignment by element count ----
    int ie = 0, iu = 1, ii = 2;
    {
        long long s[3] = { in_sizes[0], in_sizes[1], in_sizes[2] };
        ie = 0;
        if (s[1] > s[ie]) ie = 1;
        if (s[2] > s[ie]) ie = 2;
        int rest[2], k = 0;
        for (int j = 0; j < 3; ++j) if (j != ie) rest[k++] = j;
        if (s[rest[0]] >= s[rest[1]]) { iu = rest[0]; ii = rest[1]; }
        else                          { iu = rest[1]; ii = rest[0]; }
    }
    const int*   edge_index = (const int*)d_in[ie];
    const float* user_w     = (const float*)d_in[iu];
    const float* item_w     = (const float*)d_in[ii];
    float* out = (float*)d_out;   // fp32 `total`

    const int n_edges = in_sizes[ie] / 2;
    const int n_users = in_sizes[iu] / EMB;
    const int n_items = in_sizes[ii] / EMB;
    const int n_nodes = n_users + n_items;
    const int n_elems = n_nodes * EMB;
    const int NB = (n_nodes + BNODES - 1) / BNODES;   // 1172

    // ---- workspace carve (~56 MB; bufA aliases dead `pairs`) ----
    auto align_up = [](size_t x) { return (x + 1023) & ~(size_t)1023; };
    char* w = (char*)d_ws;
    int*   flag       = (int*)w; w += 1024;
    int*   bcount     = (int*)w; w += align_up((size_t)NB * sizeof(int));
    int*   bucketBase = (int*)w; w += align_up(((size_t)NB + 1) * sizeof(int));
    int*   bcur       = (int*)w; w += align_up((size_t)NB * sizeof(int));
    int*   offsets    = (int*)w; w += align_up(((size_t)n_nodes + 1) * sizeof(int));
    float* dis        = (float*)w; w += align_up((size_t)n_nodes * sizeof(float));
    int*   csr_rows   = (int*)w; w += align_up((size_t)n_edges * sizeof(int));
    size_t u_bytes = align_up((size_t)n_elems * sizeof(ushort));
    size_t p_bytes = align_up((size_t)n_edges * sizeof(uint));
    uint*   pairs = (uint*)w;
    ushort* bufA  = (ushort*)w; w += (u_bytes > p_bytes ? u_bytes : p_bytes);
    ushort* bufX  = (ushort*)w;

    const int BLK = 256;
    const int gN = (n_elems + BLK - 1) / BLK;

    // 0) edge dtype detection
    lgcn_detect_kernel<<<1, 128, 0, stream>>>(edge_index, flag);

    // 1) bucket histogram -> scan -> block-aggregated scatter -> bucket CSR
    hipMemsetAsync(bcount, 0, (size_t)NB * sizeof(int), stream);
    hipMemsetAsync(bcur, 0, (size_t)NB * sizeof(int), stream);
    lgcn_bhist_kernel<<<(n_edges + 4095) / 4096, 256, 0, stream>>>(
        edge_index, flag, bcount, n_edges, n_nodes, NB);
    lgcn_bscan_kernel<<<1, 256, 0, stream>>>(bcount, bucketBase, offsets, NB, n_nodes);
    lgcn_bscatter2_kernel<<<(n_edges + CH - 1) / CH, STH, 0, stream>>>(
        edge_index, flag, bucketBase, bcur, pairs, n_edges, n_nodes, NB);
    lgcn_bcsr_kernel<<<NB, 256, 0, stream>>>(
        pairs, bucketBase, offsets, csr_rows, dis, n_nodes);

    // 2) init: out = x (fp32), X = bf16(x)
    lgcn_init_kernel<<<gN, BLK, 0, stream>>>(user_w, item_w, out, bufX,
                                             n_users * EMB, n_elems);

    // 3) 3 pull layers (X -> A -> X -> out), one wave per node
    {
        long long n_thr = (long long)n_nodes * 64;
        int gW = (int)((n_thr + BLK - 1) / BLK);
        lgcn_gather_kernel<false><<<gW, BLK, 0, stream>>>(
            csr_rows, offsets, dis, bufX, bufA, out, n_nodes);
        lgcn_gather_kernel<false><<<gW, BLK, 0, stream>>>(
            csr_rows, offsets, dis, bufA, bufX, out, n_nodes);
        lgcn_gather_kernel<true><<<gW, BLK, 0, stream>>>(
            csr_rows, offsets, dis, bufX, nullptr, out, n_nodes);
    }
}

// Round 2
// 481.556 us; speedup vs baseline: 1.1766x; 1.0641x over previous
//
#include <hip/hip_runtime.h>
#include <hip/hip_bf16.h>

// LightGCN on MI355X — block-aggregated bucket build + batched-MLP gather.
//
// Build history: fill with 150k cursors = no contention but 249MB fragmented
// line writebacks (245us); per-edge bucket atomics on 1172 cursors = 3413
// serialized ops/address (723us). This build aggregates per block: LDS
// histogram over 1172 buckets, ONE global atomic per (block,bucket) to
// reserve a run, contiguous run writes that merge in L2. Then per-bucket
// LDS CSR finalize (round-6 bcsr, proven).
// R9: bscatter latency-bound at 4.4% occupancy -> 1024-thr blocks, CH=16384
// (245 blocks x 16 waves). Proven: 566 -> 512us.
// R10: gather was MLP-limited (chain csr->dis->row, 2KB in flight, ~2 trip
// loop). Now (a) dis[r] folded into the stored state z = dis*acc (epilogue
// uses dis[c] and dis[c]^2; masked slots read a zero row at index n_nodes),
// (b) up to 64 adjacency entries loaded in one coalesced csr read, then all
// row-gathers issued back-to-back (8KB in flight/wave). deg>64 remainder
// loop for correctness.

#ifndef EMB
#define EMB 64
#endif
#define BSHIFT 7                 // 128 nodes per bucket
#define BNODES (1 << BSHIFT)
#define NBMAX 1280               // LDS histogram capacity
#define CCAP 4800                // LDS pair-staging capacity per bucket
#define CH 16384                 // edges per bscatter block
#define STH 1024                 // bscatter threads per block

typedef unsigned int uint;
typedef unsigned short ushort;

static __device__ __forceinline__ ushort f2bf(float f) {
    __hip_bfloat16 b = __float2bfloat16(f);
    return *(ushort*)&b;
}

// u = two packed bf16; accumulate {lo,hi} into aL,aH (state is pre-scaled).
static __device__ __forceinline__ void acc2n(uint u, float& aL, float& aH) {
    union { uint x; float f; } lo, hi;
    lo.x = u << 16;
    hi.x = u & 0xffff0000u;
    aL += lo.f;
    aH += hi.f;
}

// flag = 1 if edge_index is int64 (high words of first 128 entries all zero).
__global__ void lgcn_detect_kernel(const int* __restrict__ ei, int* __restrict__ flag) {
    __shared__ int any_nz;
    if (threadIdx.x == 0) any_nz = 0;
    __syncthreads();
    if (ei[2 * threadIdx.x + 1] != 0) atomicOr(&any_nz, 1);
    __syncthreads();
    if (threadIdx.x == 0) *flag = (any_nz == 0) ? 1 : 0;
}

static __device__ __forceinline__ int load_idx(const int* __restrict__ ei,
                                               long long elem, int is64,
                                               int n_nodes) {
    int v = is64 ? ei[elem << 1] : ei[elem];
    return min(max(v, 0), n_nodes - 1);
}

// ---- build step 1: bucket histogram (LDS-staged) ----
__global__ void lgcn_bhist_kernel(const int* __restrict__ ei,
                                  const int* __restrict__ flag,
                                  int* __restrict__ bcount,
                                  int n_edges, int n_nodes, int NB) {
    __shared__ int h[NBMAX];
    int t = threadIdx.x;
    int is64 = *flag;
    for (int i = t; i < NB; i += 256) h[i] = 0;
    __syncthreads();
    long long base = (long long)blockIdx.x * 4096 + t;
    #pragma unroll
    for (int k = 0; k < 16; ++k) {
        long long e = base + (long long)k * 256;
        if (e < n_edges) {
            int c = load_idx(ei, (long long)n_edges + e, is64, n_nodes);
            atomicAdd(&h[c >> BSHIFT], 1);
        }
    }
    __syncthreads();
    for (int i = t; i < NB; i += 256) {
        int v = h[i];
        if (v) atomicAdd(&bcount[i], v);
    }
}

// ---- build step 2: exclusive scan of bucket counts (single block) ----
__global__ void lgcn_bscan_kernel(const int* __restrict__ bcount,
                                  int* __restrict__ bucketBase,
                                  int* __restrict__ offsets,
                                  int NB, int n_nodes) {
    __shared__ int tsum[256];
    int t = threadIdx.x;
    int K = (NB + 255) / 256;
    int base = t * K;
    int s = 0;
    for (int k = 0; k < K; ++k) {
        int i = base + k;
        if (i < NB) s += bcount[i];
    }
    tsum[t] = s;
    __syncthreads();
    for (int off = 1; off < 256; off <<= 1) {
        int x = (t >= off) ? tsum[t - off] : 0;
        __syncthreads();
        tsum[t] += x;
        __syncthreads();
    }
    int run = tsum[t] - s;
    for (int k = 0; k < K; ++k) {
        int i = base + k;
        if (i < NB) { bucketBase[i] = run; run += bcount[i]; }
    }
    if (t == 255) {
        bucketBase[NB] = tsum[255];
        offsets[n_nodes] = tsum[255];
    }
}

// ---- build step 3: block-aggregated pair scatter ----
// Per block: LDS bucket histogram of its CH edges, one global atomic per
// (block,bucket) to reserve a contiguous run, then write packed pairs.
// 1024 threads x 245 blocks for latency hiding (R9).
__global__ void __launch_bounds__(STH)
lgcn_bscatter2_kernel(const int* __restrict__ ei,
                      const int* __restrict__ flag,
                      const int* __restrict__ bucketBase,
                      int* __restrict__ bcur,
                      uint* __restrict__ pairs,
                      int n_edges, int n_nodes, int NB) {
    __shared__ int lcount[NBMAX];
    __shared__ int lbase[NBMAX];
    int t = threadIdx.x;
    int is64 = *flag;
    long long base = (long long)blockIdx.x * CH;
    for (int i = t; i < NB; i += STH) lcount[i] = 0;
    __syncthreads();
    // pass 1: local histogram
    for (int k = t; k < CH; k += STH) {
        long long e = base + k;
        if (e < n_edges) {
            int c = load_idx(ei, (long long)n_edges + e, is64, n_nodes);
            atomicAdd(&lcount[c >> BSHIFT], 1);
        }
    }
    __syncthreads();
    // reservation: one global atomic per non-empty bucket
    for (int i = t; i < NB; i += STH) {
        int cnt = lcount[i];
        lbase[i] = cnt ? (bucketBase[i] + atomicAdd(&bcur[i], cnt)) : 0;
        lcount[i] = 0;   // reuse as local cursor
    }
    __syncthreads();
    // pass 2: write pairs into reserved runs (contiguous per bucket-run)
    for (int k = t; k < CH; k += STH) {
        long long e = base + k;
        if (e < n_edges) {
            int r = load_idx(ei, e, is64, n_nodes);
            int c = load_idx(ei, (long long)n_edges + e, is64, n_nodes);
            int b = c >> BSHIFT;
            int pos = lbase[b] + atomicAdd(&lcount[b], 1);
            pairs[pos] = ((uint)r << BSHIFT) | (uint)(c & (BNODES - 1));
        }
    }
}

// ---- build step 4: per-bucket CSR finalize (one block per bucket) ----
__global__ void lgcn_bcsr_kernel(const uint* __restrict__ pairs,
                                 const int* __restrict__ bucketBase,
                                 int* __restrict__ offsets,
                                 int* __restrict__ csr_rows,
                                 float* __restrict__ dis,
                                 int n_nodes) {
    __shared__ int deg[BNODES];
    __shared__ int tmp[BNODES];
    __shared__ int loffx[BNODES];
    __shared__ int cur[BNODES];
    __shared__ uint lp[CCAP];
    int b = blockIdx.x;
    int t = threadIdx.x;            // 256 threads
    int nodeStart = b << BSHIFT;
    int base = bucketBase[b];
    int span = bucketBase[b + 1] - base;
    bool fits = (span <= CCAP);
    if (t < BNODES) deg[t] = 0;
    __syncthreads();
    for (int i = t; i < span; i += 256) {
        uint p = pairs[base + i];
        if (fits) lp[i] = p;
        atomicAdd(&deg[p & (BNODES - 1)], 1);
    }
    __syncthreads();
    if (t < BNODES) tmp[t] = deg[t];
    __syncthreads();
    for (int off = 1; off < BNODES; off <<= 1) {
        int x = (t < BNODES && t >= off) ? tmp[t - off] : 0;
        __syncthreads();
        if (t < BNODES) tmp[t] += x;
        __syncthreads();
    }
    if (t < BNODES) {
        int excl = tmp[t] - deg[t];
        loffx[t] = excl;
        cur[t] = 0;
        int node = nodeStart + t;
        if (node < n_nodes) {
            offsets[node] = base + excl;
            dis[node] = (deg[t] > 0) ? rsqrtf((float)deg[t]) : 0.0f;
        }
    }
    __syncthreads();
    for (int i = t; i < span; i += 256) {
        uint p = fits ? lp[i] : pairs[base + i];
        int cl = (int)(p & (BNODES - 1));
        int pos = loffx[cl] + atomicAdd(&cur[cl], 1);
        csr_rows[base + pos] = (int)(p >> BSHIFT);
    }
}

// init: out(total,fp32) = x ; X(bf16) = dis*x (pre-scaled state z0);
// also zero the dummy row (index n_nodes) of both bf16 buffers.
__global__ void lgcn_init_kernel(const float* __restrict__ user_w,
                                 const float* __restrict__ item_w,
                                 const float* __restrict__ dis,
                                 float* __restrict__ total,
                                 ushort* __restrict__ xcatb,
                                 ushort* __restrict__ abuf,
                                 int n_user_elems, int n_total_elems) {
    int i = blockIdx.x * blockDim.x + threadIdx.x;
    if (i < n_total_elems) {
        float v = (i < n_user_elems) ? user_w[i] : item_w[i - n_user_elems];
        total[i] = v;
        xcatb[i] = f2bf(dis[i >> 6] * v);
    }
    if (i < EMB) {
        xcatb[n_total_elems + i] = 0;
        abuf[n_total_elems + i] = 0;
    }
}

// gather: one wave per node; 8 lanes per edge (uint4 = 16B per lane).
// State is pre-scaled z = dis*acc, so inner loop is csr -> row only.
// Up to 64 adjacency entries loaded in one coalesced csr read; all row
// gathers for them issued back-to-back (8KB in flight per wave).
// Masked slots read the zero row at index n_nodes. deg>64: remainder loop.
template <bool LAST>
__global__ void lgcn_gather_kernel(const int* __restrict__ csr_rows,
                                   const int* __restrict__ offsets,
                                   const float* __restrict__ dis,
                                   const ushort* __restrict__ xin,
                                   ushort* __restrict__ xout,
                                   float* __restrict__ total,
                                   int n_nodes) {
    long long tid = (long long)blockIdx.x * blockDim.x + threadIdx.x;
    int c    = (int)(tid >> 6);
    int lane = threadIdx.x & 63;
    int oct  = lane >> 3;   // edge slot 0..7 within a group
    int o8   = lane & 7;    // which 16B chunk of the 128B row
    if (c >= n_nodes) return;
    int beg = offsets[c];
    int end = offsets[c + 1];
    int deg = end - beg;
    float a[8];
    #pragma unroll
    for (int k = 0; k < 8; ++k) a[k] = 0.0f;

    if (deg > 0) {
        int n1 = deg < 64 ? deg : 64;
        int ng = (n1 + 7) >> 3;        // active groups (wave-uniform)
        int rr[8];
        #pragma unroll
        for (int g = 0; g < 8; ++g) {
            int s = g * 8 + oct;
            if (g < ng) {
                int r = csr_rows[beg + (s < n1 ? s : 0)];
                rr[g] = (s < n1) ? r : n_nodes;      // zero row for tail
            } else {
                rr[g] = n_nodes;
            }
        }
        uint4 q[8];
        #pragma unroll
        for (int g = 0; g < 8; ++g)
            if (g < ng)
                q[g] = *(const uint4*)(xin + (size_t)rr[g] * EMB + o8 * 8);
        #pragma unroll
        for (int g = 0; g < 8; ++g) {
            if (g < ng) {
                acc2n(q[g].x, a[0], a[1]);
                acc2n(q[g].y, a[2], a[3]);
                acc2n(q[g].z, a[4], a[5]);
                acc2n(q[g].w, a[6], a[7]);
            }
        }
        // rare tail: deg > 64
        for (int j = beg + 64; j < end; j += 16) {
            int j0 = j + oct;
            int j1 = j + 8 + oct;
            bool v0 = j0 < end;
            bool v1 = j1 < end;
            int r0 = csr_rows[v0 ? j0 : beg]; r0 = v0 ? r0 : n_nodes;
            int r1 = csr_rows[v1 ? j1 : beg]; r1 = v1 ? r1 : n_nodes;
            uint4 q0 = *(const uint4*)(xin + (size_t)r0 * EMB + o8 * 8);
            uint4 q1 = *(const uint4*)(xin + (size_t)r1 * EMB + o8 * 8);
            acc2n(q0.x, a[0], a[1]);
            acc2n(q0.y, a[2], a[3]);
            acc2n(q0.z, a[4], a[5]);
            acc2n(q0.w, a[6], a[7]);
            acc2n(q1.x, a[0], a[1]);
            acc2n(q1.y, a[2], a[3]);
            acc2n(q1.z, a[4], a[5]);
            acc2n(q1.w, a[6], a[7]);
        }
    }

    #pragma unroll
    for (int k = 0; k < 8; ++k) {
        a[k] += __shfl_xor(a[k], 8, 64);
        a[k] += __shfl_xor(a[k], 16, 64);
        a[k] += __shfl_xor(a[k], 32, 64);
    }

    if (oct == 0) {   // lanes 0..7; lane l holds dims [8*l, 8*l+8)
        float dc = dis[c];
        float b[8];
        #pragma unroll
        for (int k = 0; k < 8; ++k) b[k] = dc * a[k];   // acc_new[c]
        size_t fo = (size_t)c * EMB + o8 * 8;
        float4* t0 = (float4*)(total + fo);
        if (!LAST) {
            // z_new[c] = dis[c] * acc_new[c]
            uint4 s;
            s.x = ((uint)f2bf(dc * b[1]) << 16) | f2bf(dc * b[0]);
            s.y = ((uint)f2bf(dc * b[3]) << 16) | f2bf(dc * b[2]);
            s.z = ((uint)f2bf(dc * b[5]) << 16) | f2bf(dc * b[4]);
            s.w = ((uint)f2bf(dc * b[7]) << 16) | f2bf(dc * b[6]);
            *(uint4*)(xout + fo) = s;
            float4 t = t0[0];
            t.x += b[0]; t.y += b[1]; t.z += b[2]; t.w += b[3];
            t0[0] = t;
            float4 u = t0[1];
            u.x += b[4]; u.y += b[5]; u.z += b[6]; u.w += b[7];
            t0[1] = u;
        } else {
            float4 t = t0[0];
            t.x = (t.x + b[0]) * 0.25f; t.y = (t.y + b[1]) * 0.25f;
            t.z = (t.z + b[2]) * 0.25f; t.w = (t.w + b[3]) * 0.25f;
            t0[0] = t;
            float4 u = t0[1];
            u.x = (u.x + b[4]) * 0.25f; u.y = (u.y + b[5]) * 0.25f;
            u.z = (u.z + b[6]) * 0.25f; u.w = (u.w + b[7]) * 0.25f;
            t0[1] = u;
        }
    }
}

extern "C" void kernel_launch(void* const* d_in, const int* in_sizes, int n_in,
                              void* d_out, int out_size, void* d_ws, size_t ws_size,
                              hipStream_t stream) {
    // ---- role assignment by element count ----
    int ie = 0, iu = 1, ii = 2;
    {
        long long s[3] = { in_sizes[0], in_sizes[1], in_sizes[2] };
        ie = 0;
        if (s[1] > s[ie]) ie = 1;
        if (s[2] > s[ie]) ie = 2;
        int rest[2], k = 0;
        for (int j = 0; j < 3; ++j) if (j != ie) rest[k++] = j;
        if (s[rest[0]] >= s[rest[1]]) { iu = rest[0]; ii = rest[1]; }
        else                          { iu = rest[1]; ii = rest[0]; }
    }
    const int*   edge_index = (const int*)d_in[ie];
    const float* user_w     = (const float*)d_in[iu];
    const float* item_w     = (const float*)d_in[ii];
    float* out = (float*)d_out;   // fp32 `total`

    const int n_edges = in_sizes[ie] / 2;
    const int n_users = in_sizes[iu] / EMB;
    const int n_items = in_sizes[ii] / EMB;
    const int n_nodes = n_users + n_items;
    const int n_elems = n_nodes * EMB;
    const int NB = (n_nodes + BNODES - 1) / BNODES;   // 1172

    // ---- workspace carve (~56 MB; bufA aliases dead `pairs`) ----
    // bf16 buffers have one extra zero row at node index n_nodes.
    auto align_up = [](size_t x) { return (x + 1023) & ~(size_t)1023; };
    char* w = (char*)d_ws;
    int*   flag       = (int*)w; w += 1024;
    int*   bcount     = (int*)w; w += align_up((size_t)NB * sizeof(int));
    int*   bucketBase = (int*)w; w += align_up(((size_t)NB + 1) * sizeof(int));
    int*   bcur       = (int*)w; w += align_up((size_t)NB * sizeof(int));
    int*   offsets    = (int*)w; w += align_up(((size_t)n_nodes + 1) * sizeof(int));
    float* dis        = (float*)w; w += align_up((size_t)n_nodes * sizeof(float));
    int*   csr_rows   = (int*)w; w += align_up((size_t)n_edges * sizeof(int));
    size_t u_bytes = align_up(((size_t)n_elems + EMB) * sizeof(ushort));
    size_t p_bytes = align_up((size_t)n_edges * sizeof(uint));
    uint*   pairs = (uint*)w;
    ushort* bufA  = (ushort*)w; w += (u_bytes > p_bytes ? u_bytes : p_bytes);
    ushort* bufX  = (ushort*)w;

    const int BLK = 256;
    const int gN = (n_elems + BLK - 1) / BLK;

    // 0) edge dtype detection
    lgcn_detect_kernel<<<1, 128, 0, stream>>>(edge_index, flag);

    // 1) bucket histogram -> scan -> block-aggregated scatter -> bucket CSR
    hipMemsetAsync(bcount, 0, (size_t)NB * sizeof(int), stream);
    hipMemsetAsync(bcur, 0, (size_t)NB * sizeof(int), stream);
    lgcn_bhist_kernel<<<(n_edges + 4095) / 4096, 256, 0, stream>>>(
        edge_index, flag, bcount, n_edges, n_nodes, NB);
    lgcn_bscan_kernel<<<1, 256, 0, stream>>>(bcount, bucketBase, offsets, NB, n_nodes);
    lgcn_bscatter2_kernel<<<(n_edges + CH - 1) / CH, STH, 0, stream>>>(
        edge_index, flag, bucketBase, bcur, pairs, n_edges, n_nodes, NB);
    lgcn_bcsr_kernel<<<NB, 256, 0, stream>>>(
        pairs, bucketBase, offsets, csr_rows, dis, n_nodes);

    // 2) init: out = x (fp32), X = bf16(dis*x), zero rows (needs dis -> after bcsr)
    lgcn_init_kernel<<<gN, BLK, 0, stream>>>(user_w, item_w, dis, out, bufX, bufA,
                                             n_users * EMB, n_elems);

    // 3) 3 pull layers (X -> A -> X -> out), one wave per node
    {
        long long n_thr = (long long)n_nodes * 64;
        int gW = (int)((n_thr + BLK - 1) / BLK);
        lgcn_gather_kernel<false><<<gW, BLK, 0, stream>>>(
            csr_rows, offsets, dis, bufX, bufA, out, n_nodes);
        lgcn_gather_kernel<false><<<gW, BLK, 0, stream>>>(
            csr_rows, offsets, dis, bufA, bufX, out, n_nodes);
        lgcn_gather_kernel<true><<<gW, BLK, 0, stream>>>(
            csr_rows, offsets, dis, bufX, nullptr, out, n_nodes);
    }
}

// Round 3
// 459.487 us; speedup vs baseline: 1.2331x; 1.0480x over previous
//
#include <hip/hip_runtime.h>
#include <hip/hip_fp16.h>

// LightGCN on MI355X — block-aggregated bucket build + batched-MLP gather,
// deferred-total fp16 pipeline.
//
// Build: LDS bucket histogram -> scan -> block-aggregated pair scatter (one
// global atomic per (block,bucket), contiguous runs) -> per-bucket LDS CSR
// finalize. R9: bscatter 1024thr/CH=16384 (proven 566->512).
// R10: batched 64-entry adjacency read + dis folded into state (512->481).
// R11: gathers were carrying 76.8MB/dispatch of fp32 `total` r-m-w on a
// kernel pinned at ~3.7TB/s. Total is now DEFERRED: gathers write only the
// fp16 propagated state z_k = dis*acc_k; a final streaming pass computes
// out = 0.25*x + (0.25/dis)*(z1+z2+z3). State moved bf16->fp16 (10-bit
// mantissa, |z|<=2) so the z-reconstruction adds ~1e-5 error. init fused
// into bcsr (which computes dis); detect+memsets merged into one setup
// kernel. z3 aliases dead `pairs`.

#ifndef EMB
#define EMB 64
#endif
#define BSHIFT 7                 // 128 nodes per bucket
#define BNODES (1 << BSHIFT)
#define NBMAX 1280               // LDS histogram capacity
#define CCAP 4800                // LDS pair-staging capacity per bucket
#define CH 16384                 // edges per bscatter block
#define STH 1024                 // bscatter threads per block

typedef unsigned int uint;
typedef unsigned short ushort;

static __device__ __forceinline__ ushort f2h(float f) {
    __half h = __float2half(f);
    return *(ushort*)&h;
}

static __device__ __forceinline__ void acc2h(uint u, float& aL, float& aH) {
    __half2 h = *(__half2*)&u;
    float2 f = __half22float2(h);
    aL += f.x;
    aH += f.y;
}

static __device__ __forceinline__ float2 h2f2(uint u) {
    __half2 h = *(__half2*)&u;
    return __half22float2(h);
}

// ---- setup: dtype detect + zero bucket counters + zero dummy rows ----
__global__ void lgcn_setup_kernel(const int* __restrict__ ei,
                                  int* __restrict__ flag,
                                  int* __restrict__ bcount,
                                  int* __restrict__ bcur,
                                  ushort* __restrict__ z0,
                                  ushort* __restrict__ z1,
                                  ushort* __restrict__ z2,
                                  ushort* __restrict__ z3,
                                  int NB, int n_elems) {
    __shared__ int any_nz;
    int t = threadIdx.x;
    if (t == 0) any_nz = 0;
    __syncthreads();
    if (t < 128 && ei[2 * t + 1] != 0) atomicOr(&any_nz, 1);
    for (int i = t; i < NB; i += 256) { bcount[i] = 0; bcur[i] = 0; }
    if (t < EMB) {
        z0[n_elems + t] = 0;
        z1[n_elems + t] = 0;
        z2[n_elems + t] = 0;
        z3[n_elems + t] = 0;   // beyond pairs' 16MB within the 19.2MB slot
    }
    __syncthreads();
    if (t == 0) *flag = (any_nz == 0) ? 1 : 0;
}

static __device__ __forceinline__ int load_idx(const int* __restrict__ ei,
                                               long long elem, int is64,
                                               int n_nodes) {
    int v = is64 ? ei[elem << 1] : ei[elem];
    return min(max(v, 0), n_nodes - 1);
}

// ---- build step 1: bucket histogram (LDS-staged) ----
__global__ void lgcn_bhist_kernel(const int* __restrict__ ei,
                                  const int* __restrict__ flag,
                                  int* __restrict__ bcount,
                                  int n_edges, int n_nodes, int NB) {
    __shared__ int h[NBMAX];
    int t = threadIdx.x;
    int is64 = *flag;
    for (int i = t; i < NB; i += 256) h[i] = 0;
    __syncthreads();
    long long base = (long long)blockIdx.x * 4096 + t;
    #pragma unroll
    for (int k = 0; k < 16; ++k) {
        long long e = base + (long long)k * 256;
        if (e < n_edges) {
            int c = load_idx(ei, (long long)n_edges + e, is64, n_nodes);
            atomicAdd(&h[c >> BSHIFT], 1);
        }
    }
    __syncthreads();
    for (int i = t; i < NB; i += 256) {
        int v = h[i];
        if (v) atomicAdd(&bcount[i], v);
    }
}

// ---- build step 2: exclusive scan of bucket counts (single block) ----
__global__ void lgcn_bscan_kernel(const int* __restrict__ bcount,
                                  int* __restrict__ bucketBase,
                                  int* __restrict__ offsets,
                                  int NB, int n_nodes) {
    __shared__ int tsum[256];
    int t = threadIdx.x;
    int K = (NB + 255) / 256;
    int base = t * K;
    int s = 0;
    for (int k = 0; k < K; ++k) {
        int i = base + k;
        if (i < NB) s += bcount[i];
    }
    tsum[t] = s;
    __syncthreads();
    for (int off = 1; off < 256; off <<= 1) {
        int x = (t >= off) ? tsum[t - off] : 0;
        __syncthreads();
        tsum[t] += x;
        __syncthreads();
    }
    int run = tsum[t] - s;
    for (int k = 0; k < K; ++k) {
        int i = base + k;
        if (i < NB) { bucketBase[i] = run; run += bcount[i]; }
    }
    if (t == 255) {
        bucketBase[NB] = tsum[255];
        offsets[n_nodes] = tsum[255];
    }
}

// ---- build step 3: block-aggregated pair scatter ----
__global__ void __launch_bounds__(STH)
lgcn_bscatter2_kernel(const int* __restrict__ ei,
                      const int* __restrict__ flag,
                      const int* __restrict__ bucketBase,
                      int* __restrict__ bcur,
                      uint* __restrict__ pairs,
                      int n_edges, int n_nodes, int NB) {
    __shared__ int lcount[NBMAX];
    __shared__ int lbase[NBMAX];
    int t = threadIdx.x;
    int is64 = *flag;
    long long base = (long long)blockIdx.x * CH;
    for (int i = t; i < NB; i += STH) lcount[i] = 0;
    __syncthreads();
    // pass 1: local histogram
    for (int k = t; k < CH; k += STH) {
        long long e = base + k;
        if (e < n_edges) {
            int c = load_idx(ei, (long long)n_edges + e, is64, n_nodes);
            atomicAdd(&lcount[c >> BSHIFT], 1);
        }
    }
    __syncthreads();
    // reservation: one global atomic per non-empty bucket
    for (int i = t; i < NB; i += STH) {
        int cnt = lcount[i];
        lbase[i] = cnt ? (bucketBase[i] + atomicAdd(&bcur[i], cnt)) : 0;
        lcount[i] = 0;   // reuse as local cursor
    }
    __syncthreads();
    // pass 2: write pairs into reserved runs (contiguous per bucket-run)
    for (int k = t; k < CH; k += STH) {
        long long e = base + k;
        if (e < n_edges) {
            int r = load_idx(ei, e, is64, n_nodes);
            int c = load_idx(ei, (long long)n_edges + e, is64, n_nodes);
            int b = c >> BSHIFT;
            int pos = lbase[b] + atomicAdd(&lcount[b], 1);
            pairs[pos] = ((uint)r << BSHIFT) | (uint)(c & (BNODES - 1));
        }
    }
}

// ---- build step 4: per-bucket CSR finalize + fused z0 init ----
__global__ void lgcn_bcsr_kernel(const uint* __restrict__ pairs,
                                 const int* __restrict__ bucketBase,
                                 const float* __restrict__ user_w,
                                 const float* __restrict__ item_w,
                                 int* __restrict__ offsets,
                                 int* __restrict__ csr_rows,
                                 float* __restrict__ dis,
                                 ushort* __restrict__ z0,
                                 int n_user_elems, int n_nodes) {
    __shared__ int deg[BNODES];
    __shared__ int tmp[BNODES];
    __shared__ int loffx[BNODES];
    __shared__ int cur[BNODES];
    __shared__ float disL[BNODES];
    __shared__ uint lp[CCAP];
    int b = blockIdx.x;
    int t = threadIdx.x;            // 256 threads
    int nodeStart = b << BSHIFT;
    int base = bucketBase[b];
    int span = bucketBase[b + 1] - base;
    bool fits = (span <= CCAP);
    if (t < BNODES) deg[t] = 0;
    __syncthreads();
    for (int i = t; i < span; i += 256) {
        uint p = pairs[base + i];
        if (fits) lp[i] = p;
        atomicAdd(&deg[p & (BNODES - 1)], 1);
    }
    __syncthreads();
    if (t < BNODES) tmp[t] = deg[t];
    __syncthreads();
    for (int off = 1; off < BNODES; off <<= 1) {
        int x = (t < BNODES && t >= off) ? tmp[t - off] : 0;
        __syncthreads();
        if (t < BNODES) tmp[t] += x;
        __syncthreads();
    }
    if (t < BNODES) {
        int excl = tmp[t] - deg[t];
        loffx[t] = excl;
        cur[t] = 0;
        float d = (deg[t] > 0) ? rsqrtf((float)deg[t]) : 0.0f;
        disL[t] = d;
        int node = nodeStart + t;
        if (node < n_nodes) {
            offsets[node] = base + excl;
            dis[node] = d;
        }
    }
    __syncthreads();
    for (int i = t; i < span; i += 256) {
        uint p = fits ? lp[i] : pairs[base + i];
        int cl = (int)(p & (BNODES - 1));
        int pos = loffx[cl] + atomicAdd(&cur[cl], 1);
        csr_rows[base + pos] = (int)(p >> BSHIFT);
    }
    // fused init: z0 rows for this bucket's nodes, z0 = fp16(dis * x)
    int eBase = nodeStart << 6;               // first element of this bucket
    for (int e4 = t; e4 < (BNODES << 4); e4 += 256) {   // float4 granules
        int e = e4 << 2;
        int node = nodeStart + (e >> 6);
        if (node < n_nodes) {
            int gi = eBase + e;
            float4 v = (gi < n_user_elems)
                ? *(const float4*)(user_w + gi)
                : *(const float4*)(item_w + (gi - n_user_elems));
            float d = disL[e >> 6];
            ushort4 o;
            o.x = f2h(d * v.x); o.y = f2h(d * v.y);
            o.z = f2h(d * v.z); o.w = f2h(d * v.w);
            *(ushort4*)(z0 + gi) = o;
        }
    }
}

// gather: one wave per node; 8 lanes per edge (uint4 = 16B per lane).
// State pre-scaled z = dis*acc (fp16): inner loop is csr -> row only.
// Up to 64 adjacency entries in one coalesced csr read; all row gathers
// issued back-to-back (8KB in flight/wave). Masked slots read the zero
// row at index n_nodes. deg>64: remainder loop. Writes z_out only.
__global__ void lgcn_gather_kernel(const int* __restrict__ csr_rows,
                                   const int* __restrict__ offsets,
                                   const float* __restrict__ dis,
                                   const ushort* __restrict__ zin,
                                   ushort* __restrict__ zout,
                                   int n_nodes) {
    long long tid = (long long)blockIdx.x * blockDim.x + threadIdx.x;
    int c    = (int)(tid >> 6);
    int lane = threadIdx.x & 63;
    int oct  = lane >> 3;   // edge slot 0..7 within a group
    int o8   = lane & 7;    // which 16B chunk of the 128B row
    if (c >= n_nodes) return;
    int beg = offsets[c];
    int end = offsets[c + 1];
    int deg = end - beg;
    float a[8];
    #pragma unroll
    for (int k = 0; k < 8; ++k) a[k] = 0.0f;

    if (deg > 0) {
        int n1 = deg < 64 ? deg : 64;
        int ng = (n1 + 7) >> 3;        // active groups (wave-uniform)
        int rr[8];
        #pragma unroll
        for (int g = 0; g < 8; ++g) {
            int s = g * 8 + oct;
            if (g < ng) {
                int r = csr_rows[beg + (s < n1 ? s : 0)];
                rr[g] = (s < n1) ? r : n_nodes;      // zero row for tail
            } else {
                rr[g] = n_nodes;
            }
        }
        uint4 q[8];
        #pragma unroll
        for (int g = 0; g < 8; ++g)
            if (g < ng)
                q[g] = *(const uint4*)(zin + (size_t)rr[g] * EMB + o8 * 8);
        #pragma unroll
        for (int g = 0; g < 8; ++g) {
            if (g < ng) {
                acc2h(q[g].x, a[0], a[1]);
                acc2h(q[g].y, a[2], a[3]);
                acc2h(q[g].z, a[4], a[5]);
                acc2h(q[g].w, a[6], a[7]);
            }
        }
        // rare tail: deg > 64
        for (int j = beg + 64; j < end; j += 16) {
            int j0 = j + oct;
            int j1 = j + 8 + oct;
            bool v0 = j0 < end;
            bool v1 = j1 < end;
            int r0 = csr_rows[v0 ? j0 : beg]; r0 = v0 ? r0 : n_nodes;
            int r1 = csr_rows[v1 ? j1 : beg]; r1 = v1 ? r1 : n_nodes;
            uint4 q0 = *(const uint4*)(zin + (size_t)r0 * EMB + o8 * 8);
            uint4 q1 = *(const uint4*)(zin + (size_t)r1 * EMB + o8 * 8);
            acc2h(q0.x, a[0], a[1]);
            acc2h(q0.y, a[2], a[3]);
            acc2h(q0.z, a[4], a[5]);
            acc2h(q0.w, a[6], a[7]);
            acc2h(q1.x, a[0], a[1]);
            acc2h(q1.y, a[2], a[3]);
            acc2h(q1.z, a[4], a[5]);
            acc2h(q1.w, a[6], a[7]);
        }
    }

    #pragma unroll
    for (int k = 0; k < 8; ++k) {
        a[k] += __shfl_xor(a[k], 8, 64);
        a[k] += __shfl_xor(a[k], 16, 64);
        a[k] += __shfl_xor(a[k], 32, 64);
    }

    if (oct == 0) {   // lanes 0..7; lane l holds dims [8*l, 8*l+8)
        float dc = dis[c];
        float s2 = dc * dc;               // z_new = dis^2 * sum
        size_t fo = (size_t)c * EMB + o8 * 8;
        uint4 s;
        s.x = ((uint)f2h(s2 * a[1]) << 16) | f2h(s2 * a[0]);
        s.y = ((uint)f2h(s2 * a[3]) << 16) | f2h(s2 * a[2]);
        s.z = ((uint)f2h(s2 * a[5]) << 16) | f2h(s2 * a[4]);
        s.w = ((uint)f2h(s2 * a[7]) << 16) | f2h(s2 * a[6]);
        *(uint4*)(zout + fo) = s;
    }
}

// final: out = 0.25*x + (0.25/dis)*(z1+z2+z3); 8 elems per thread.
__global__ void lgcn_final_kernel(const float* __restrict__ user_w,
                                  const float* __restrict__ item_w,
                                  const float* __restrict__ dis,
                                  const ushort* __restrict__ z1,
                                  const ushort* __restrict__ z2,
                                  const ushort* __restrict__ z3,
                                  float* __restrict__ out,
                                  int n_user_elems, int n_total_elems) {
    int i8 = blockIdx.x * blockDim.x + threadIdx.x;
    int base = i8 << 3;
    if (base >= n_total_elems) return;
    int node = base >> 6;
    float dc = dis[node];
    float inv = (dc > 0.0f) ? 0.25f / dc : 0.0f;
    uint4 a = *(const uint4*)(z1 + base);
    uint4 b = *(const uint4*)(z2 + base);
    uint4 c = *(const uint4*)(z3 + base);
    float s[8];
    {
        float2 p, q, r;
        p = h2f2(a.x); q = h2f2(b.x); r = h2f2(c.x);
        s[0] = p.x + q.x + r.x; s[1] = p.y + q.y + r.y;
        p = h2f2(a.y); q = h2f2(b.y); r = h2f2(c.y);
        s[2] = p.x + q.x + r.x; s[3] = p.y + q.y + r.y;
        p = h2f2(a.z); q = h2f2(b.z); r = h2f2(c.z);
        s[4] = p.x + q.x + r.x; s[5] = p.y + q.y + r.y;
        p = h2f2(a.w); q = h2f2(b.w); r = h2f2(c.w);
        s[6] = p.x + q.x + r.x; s[7] = p.y + q.y + r.y;
    }
    float4 x0, x1;
    if (base < n_user_elems) {
        x0 = *(const float4*)(user_w + base);
        x1 = *(const float4*)(user_w + base + 4);
    } else {
        int j = base - n_user_elems;
        x0 = *(const float4*)(item_w + j);
        x1 = *(const float4*)(item_w + j + 4);
    }
    float4 o0, o1;
    o0.x = 0.25f * x0.x + inv * s[0];
    o0.y = 0.25f * x0.y + inv * s[1];
    o0.z = 0.25f * x0.z + inv * s[2];
    o0.w = 0.25f * x0.w + inv * s[3];
    o1.x = 0.25f * x1.x + inv * s[4];
    o1.y = 0.25f * x1.y + inv * s[5];
    o1.z = 0.25f * x1.z + inv * s[6];
    o1.w = 0.25f * x1.w + inv * s[7];
    *(float4*)(out + base) = o0;
    *(float4*)(out + base + 4) = o1;
}

extern "C" void kernel_launch(void* const* d_in, const int* in_sizes, int n_in,
                              void* d_out, int out_size, void* d_ws, size_t ws_size,
                              hipStream_t stream) {
    // ---- role assignment by element count ----
    int ie = 0, iu = 1, ii = 2;
    {
        long long s[3] = { in_sizes[0], in_sizes[1], in_sizes[2] };
        ie = 0;
        if (s[1] > s[ie]) ie = 1;
        if (s[2] > s[ie]) ie = 2;
        int rest[2], k = 0;
        for (int j = 0; j < 3; ++j) if (j != ie) rest[k++] = j;
        if (s[rest[0]] >= s[rest[1]]) { iu = rest[0]; ii = rest[1]; }
        else                          { iu = rest[1]; ii = rest[0]; }
    }
    const int*   edge_index = (const int*)d_in[ie];
    const float* user_w     = (const float*)d_in[iu];
    const float* item_w     = (const float*)d_in[ii];
    float* out = (float*)d_out;

    const int n_edges = in_sizes[ie] / 2;
    const int n_users = in_sizes[iu] / EMB;
    const int n_items = in_sizes[ii] / EMB;
    const int n_nodes = n_users + n_items;
    const int n_elems = n_nodes * EMB;
    const int NB = (n_nodes + BNODES - 1) / BNODES;   // 1172

    // ---- workspace carve (~93 MB; z3 aliases dead `pairs`) ----
    // fp16 state buffers each have one extra zero row at node index n_nodes.
    auto align_up = [](size_t x) { return (x + 1023) & ~(size_t)1023; };
    char* w = (char*)d_ws;
    int*   flag       = (int*)w; w += 1024;
    int*   bcount     = (int*)w; w += align_up((size_t)NB * sizeof(int));
    int*   bucketBase = (int*)w; w += align_up(((size_t)NB + 1) * sizeof(int));
    int*   bcur       = (int*)w; w += align_up((size_t)NB * sizeof(int));
    int*   offsets    = (int*)w; w += align_up(((size_t)n_nodes + 1) * sizeof(int));
    float* dis        = (float*)w; w += align_up((size_t)n_nodes * sizeof(float));
    int*   csr_rows   = (int*)w; w += align_up((size_t)n_edges * sizeof(int));
    size_t u_bytes = align_up(((size_t)n_elems + EMB) * sizeof(ushort));
    size_t p_bytes = align_up((size_t)n_edges * sizeof(uint));
    size_t slot0   = (u_bytes > p_bytes ? u_bytes : p_bytes);
    uint*   pairs = (uint*)w;
    ushort* z3    = (ushort*)w; w += slot0;      // z3 overlays dead pairs
    ushort* z0    = (ushort*)w; w += u_bytes;
    ushort* z1    = (ushort*)w; w += u_bytes;
    ushort* z2    = (ushort*)w; w += u_bytes;

    // 0) setup: dtype detect + zero counters + zero dummy rows
    lgcn_setup_kernel<<<1, 256, 0, stream>>>(edge_index, flag, bcount, bcur,
                                             z0, z1, z2, z3, NB, n_elems);

    // 1) bucket histogram -> scan -> block-aggregated scatter -> bucket CSR(+init)
    lgcn_bhist_kernel<<<(n_edges + 4095) / 4096, 256, 0, stream>>>(
        edge_index, flag, bcount, n_edges, n_nodes, NB);
    lgcn_bscan_kernel<<<1, 256, 0, stream>>>(bcount, bucketBase, offsets, NB, n_nodes);
    lgcn_bscatter2_kernel<<<(n_edges + CH - 1) / CH, STH, 0, stream>>>(
        edge_index, flag, bucketBase, bcur, pairs, n_edges, n_nodes, NB);
    lgcn_bcsr_kernel<<<NB, 256, 0, stream>>>(
        pairs, bucketBase, user_w, item_w, offsets, csr_rows, dis, z0,
        n_users * EMB, n_nodes);

    // 2) 3 pull layers: z0 -> z1 -> z2 -> z3 (z writes only, no total)
    {
        const int BLK = 256;
        long long n_thr = (long long)n_nodes * 64;
        int gW = (int)((n_thr + BLK - 1) / BLK);
        lgcn_gather_kernel<<<gW, BLK, 0, stream>>>(
            csr_rows, offsets, dis, z0, z1, n_nodes);
        lgcn_gather_kernel<<<gW, BLK, 0, stream>>>(
            csr_rows, offsets, dis, z1, z2, n_nodes);
        lgcn_gather_kernel<<<gW, BLK, 0, stream>>>(
            csr_rows, offsets, dis, z2, z3, n_nodes);
    }

    // 3) final: out = 0.25*x + (0.25/dis)*(z1+z2+z3)
    {
        const int BLK = 256;
        int nthr = n_elems / 8;
        lgcn_final_kernel<<<(nthr + BLK - 1) / BLK, BLK, 0, stream>>>(
            user_w, item_w, dis, z1, z2, z3, out, n_users * EMB, n_elems);
    }
}

// Round 4
// 434.004 us; speedup vs baseline: 1.3055x; 1.0587x over previous
//
#include <hip/hip_runtime.h>
#include <hip/hip_fp16.h>

// LightGCN on MI355X — block-aggregated bucket build + batched-MLP gather,
// deferred-total fp16 pipeline.
//
// Build: LDS bucket histogram -> scan -> block-aggregated pair scatter ->
// per-bucket LDS CSR finalize.
// R9:  bscatter 1024thr/CH=16384 (566->512).
// R10: batched 64-entry adjacency read + dis folded into state (512->481).
// R11: total deferred out of gathers; fp16 state; final streaming pass
//      (481->459).
// R12: bscatter pass-2 scattered 4B stores touched ~64 lines/wave-store
//      (WRITE 78-97MB for 16MB of pairs, ~6x amplification; store-pipe
//      bound at 75us). Pairs now STAGED IN LDS grouped by bucket (64KB
//      stage + 32KB bucket-ids; grid 245 blocks = 1 block/CU so LDS is
//      free), then written run-contiguously: consecutive lanes ->
//      consecutive addresses, full lines except run boundaries.

#ifndef EMB
#define EMB 64
#endif
#define BSHIFT 7                 // 128 nodes per bucket
#define BNODES (1 << BSHIFT)
#define NBMAX 1280               // LDS histogram capacity
#define CCAP 4800                // LDS pair-staging capacity per bucket
#define CH 16384                 // edges per bscatter block
#define STH 1024                 // bscatter threads per block

typedef unsigned int uint;
typedef unsigned short ushort;

static __device__ __forceinline__ ushort f2h(float f) {
    __half h = __float2half(f);
    return *(ushort*)&h;
}

static __device__ __forceinline__ void acc2h(uint u, float& aL, float& aH) {
    __half2 h = *(__half2*)&u;
    float2 f = __half22float2(h);
    aL += f.x;
    aH += f.y;
}

static __device__ __forceinline__ float2 h2f2(uint u) {
    __half2 h = *(__half2*)&u;
    return __half22float2(h);
}

// ---- setup: dtype detect + zero bucket counters + zero dummy rows ----
__global__ void lgcn_setup_kernel(const int* __restrict__ ei,
                                  int* __restrict__ flag,
                                  int* __restrict__ bcount,
                                  int* __restrict__ bcur,
                                  ushort* __restrict__ z0,
                                  ushort* __restrict__ z1,
                                  ushort* __restrict__ z2,
                                  ushort* __restrict__ z3,
                                  int NB, int n_elems) {
    __shared__ int any_nz;
    int t = threadIdx.x;
    if (t == 0) any_nz = 0;
    __syncthreads();
    if (t < 128 && ei[2 * t + 1] != 0) atomicOr(&any_nz, 1);
    for (int i = t; i < NB; i += 256) { bcount[i] = 0; bcur[i] = 0; }
    if (t < EMB) {
        z0[n_elems + t] = 0;
        z1[n_elems + t] = 0;
        z2[n_elems + t] = 0;
        z3[n_elems + t] = 0;
    }
    __syncthreads();
    if (t == 0) *flag = (any_nz == 0) ? 1 : 0;
}

static __device__ __forceinline__ int load_idx(const int* __restrict__ ei,
                                               long long elem, int is64,
                                               int n_nodes) {
    int v = is64 ? ei[elem << 1] : ei[elem];
    return min(max(v, 0), n_nodes - 1);
}

// ---- build step 1: bucket histogram (LDS-staged) ----
__global__ void lgcn_bhist_kernel(const int* __restrict__ ei,
                                  const int* __restrict__ flag,
                                  int* __restrict__ bcount,
                                  int n_edges, int n_nodes, int NB) {
    __shared__ int h[NBMAX];
    int t = threadIdx.x;
    int is64 = *flag;
    for (int i = t; i < NB; i += 256) h[i] = 0;
    __syncthreads();
    long long base = (long long)blockIdx.x * 4096 + t;
    #pragma unroll
    for (int k = 0; k < 16; ++k) {
        long long e = base + (long long)k * 256;
        if (e < n_edges) {
            int c = load_idx(ei, (long long)n_edges + e, is64, n_nodes);
            atomicAdd(&h[c >> BSHIFT], 1);
        }
    }
    __syncthreads();
    for (int i = t; i < NB; i += 256) {
        int v = h[i];
        if (v) atomicAdd(&bcount[i], v);
    }
}

// ---- build step 2: exclusive scan of bucket counts (single block) ----
__global__ void lgcn_bscan_kernel(const int* __restrict__ bcount,
                                  int* __restrict__ bucketBase,
                                  int* __restrict__ offsets,
                                  int NB, int n_nodes) {
    __shared__ int tsum[256];
    int t = threadIdx.x;
    int K = (NB + 255) / 256;
    int base = t * K;
    int s = 0;
    for (int k = 0; k < K; ++k) {
        int i = base + k;
        if (i < NB) s += bcount[i];
    }
    tsum[t] = s;
    __syncthreads();
    for (int off = 1; off < 256; off <<= 1) {
        int x = (t >= off) ? tsum[t - off] : 0;
        __syncthreads();
        tsum[t] += x;
        __syncthreads();
    }
    int run = tsum[t] - s;
    for (int k = 0; k < K; ++k) {
        int i = base + k;
        if (i < NB) { bucketBase[i] = run; run += bcount[i]; }
    }
    if (t == 255) {
        bucketBase[NB] = tsum[255];
        offsets[n_nodes] = tsum[255];
    }
}

// ---- build step 3: block-aggregated pair scatter, LDS-staged (R12) ----
// Per block: LDS histogram -> local exclusive scan (staging layout) ->
// one global atomic per (block,bucket) to reserve the global run ->
// stage pairs grouped-by-bucket in LDS -> coalesced run-contiguous writes.
__global__ void __launch_bounds__(STH)
lgcn_bscatter3_kernel(const int* __restrict__ ei,
                      const int* __restrict__ flag,
                      const int* __restrict__ bucketBase,
                      int* __restrict__ bcur,
                      uint* __restrict__ pairs,
                      int n_edges, int n_nodes, int NB) {
    __shared__ int lcount[NBMAX];   // histogram, then staging cursor
    __shared__ int lloc[NBMAX];     // local staging base per bucket
    __shared__ int ldelta[NBMAX];   // global_run_base - local_base
    __shared__ int tsum[STH];
    __shared__ int ltot;
    __shared__ uint stage[CH];      // 64 KB pair staging
    __shared__ ushort stageb[CH];   // 32 KB bucket id per staged pair
    int t = threadIdx.x;
    int is64 = *flag;
    long long base = (long long)blockIdx.x * CH;
    for (int i = t; i < NB; i += STH) lcount[i] = 0;
    __syncthreads();
    // pass 1: local histogram of target buckets
    for (int k = t; k < CH; k += STH) {
        long long e = base + k;
        if (e < n_edges) {
            int c = load_idx(ei, (long long)n_edges + e, is64, n_nodes);
            atomicAdd(&lcount[c >> BSHIFT], 1);
        }
    }
    __syncthreads();
    // local exclusive scan lcount -> lloc (staging layout)
    {
        int K = (NB + STH - 1) / STH;   // 2 for NB<=2048
        int cbase = t * K;
        int s = 0;
        for (int k = 0; k < K; ++k) {
            int i = cbase + k;
            if (i < NB) s += lcount[i];
        }
        tsum[t] = s;
        __syncthreads();
        for (int off = 1; off < STH; off <<= 1) {
            int x = (t >= off) ? tsum[t - off] : 0;
            __syncthreads();
            tsum[t] += x;
            __syncthreads();
        }
        int run = tsum[t] - s;
        for (int k = 0; k < K; ++k) {
            int i = cbase + k;
            if (i < NB) { lloc[i] = run; run += lcount[i]; }
        }
        if (t == STH - 1) ltot = tsum[t];
    }
    __syncthreads();
    // reservation: one global atomic per non-empty bucket
    for (int i = t; i < NB; i += STH) {
        int cnt = lcount[i];
        ldelta[i] = cnt ? (bucketBase[i] + atomicAdd(&bcur[i], cnt) - lloc[i]) : 0;
        lcount[i] = 0;   // reuse as staging cursor
    }
    __syncthreads();
    // pass 2: stage pairs grouped by bucket in LDS
    for (int k = t; k < CH; k += STH) {
        long long e = base + k;
        if (e < n_edges) {
            int r = load_idx(ei, e, is64, n_nodes);
            int c = load_idx(ei, (long long)n_edges + e, is64, n_nodes);
            int b = c >> BSHIFT;
            int pos = lloc[b] + atomicAdd(&lcount[b], 1);
            stage[pos] = ((uint)r << BSHIFT) | (uint)(c & (BNODES - 1));
            stageb[pos] = (ushort)b;
        }
    }
    __syncthreads();
    // pass 3: coalesced run-contiguous global writes
    int tot = ltot;
    for (int k = t; k < tot; k += STH) {
        pairs[ldelta[stageb[k]] + k] = stage[k];
    }
}

// ---- build step 4: per-bucket CSR finalize + fused z0 init ----
__global__ void lgcn_bcsr_kernel(const uint* __restrict__ pairs,
                                 const int* __restrict__ bucketBase,
                                 const float* __restrict__ user_w,
                                 const float* __restrict__ item_w,
                                 int* __restrict__ offsets,
                                 int* __restrict__ csr_rows,
                                 float* __restrict__ dis,
                                 ushort* __restrict__ z0,
                                 int n_user_elems, int n_nodes) {
    __shared__ int deg[BNODES];
    __shared__ int tmp[BNODES];
    __shared__ int loffx[BNODES];
    __shared__ int cur[BNODES];
    __shared__ float disL[BNODES];
    __shared__ uint lp[CCAP];
    int b = blockIdx.x;
    int t = threadIdx.x;            // 256 threads
    int nodeStart = b << BSHIFT;
    int base = bucketBase[b];
    int span = bucketBase[b + 1] - base;
    bool fits = (span <= CCAP);
    if (t < BNODES) deg[t] = 0;
    __syncthreads();
    for (int i = t; i < span; i += 256) {
        uint p = pairs[base + i];
        if (fits) lp[i] = p;
        atomicAdd(&deg[p & (BNODES - 1)], 1);
    }
    __syncthreads();
    if (t < BNODES) tmp[t] = deg[t];
    __syncthreads();
    for (int off = 1; off < BNODES; off <<= 1) {
        int x = (t < BNODES && t >= off) ? tmp[t - off] : 0;
        __syncthreads();
        if (t < BNODES) tmp[t] += x;
        __syncthreads();
    }
    if (t < BNODES) {
        int excl = tmp[t] - deg[t];
        loffx[t] = excl;
        cur[t] = 0;
        float d = (deg[t] > 0) ? rsqrtf((float)deg[t]) : 0.0f;
        disL[t] = d;
        int node = nodeStart + t;
        if (node < n_nodes) {
            offsets[node] = base + excl;
            dis[node] = d;
        }
    }
    __syncthreads();
    for (int i = t; i < span; i += 256) {
        uint p = fits ? lp[i] : pairs[base + i];
        int cl = (int)(p & (BNODES - 1));
        int pos = loffx[cl] + atomicAdd(&cur[cl], 1);
        csr_rows[base + pos] = (int)(p >> BSHIFT);
    }
    // fused init: z0 rows for this bucket's nodes, z0 = fp16(dis * x)
    int eBase = nodeStart << 6;               // first element of this bucket
    for (int e4 = t; e4 < (BNODES << 4); e4 += 256) {   // float4 granules
        int e = e4 << 2;
        int node = nodeStart + (e >> 6);
        if (node < n_nodes) {
            int gi = eBase + e;
            float4 v = (gi < n_user_elems)
                ? *(const float4*)(user_w + gi)
                : *(const float4*)(item_w + (gi - n_user_elems));
            float d = disL[e >> 6];
            ushort4 o;
            o.x = f2h(d * v.x); o.y = f2h(d * v.y);
            o.z = f2h(d * v.z); o.w = f2h(d * v.w);
            *(ushort4*)(z0 + gi) = o;
        }
    }
}

// gather: one wave per node; 8 lanes per edge (uint4 = 16B per lane).
// State pre-scaled z = dis*acc (fp16): inner loop is csr -> row only.
// Up to 64 adjacency entries in one coalesced csr read; all row gathers
// issued back-to-back (8KB in flight/wave). Masked slots read the zero
// row at index n_nodes. deg>64: remainder loop. Writes z_out only.
__global__ void lgcn_gather_kernel(const int* __restrict__ csr_rows,
                                   const int* __restrict__ offsets,
                                   const float* __restrict__ dis,
                                   const ushort* __restrict__ zin,
                                   ushort* __restrict__ zout,
                                   int n_nodes) {
    long long tid = (long long)blockIdx.x * blockDim.x + threadIdx.x;
    int c    = (int)(tid >> 6);
    int lane = threadIdx.x & 63;
    int oct  = lane >> 3;   // edge slot 0..7 within a group
    int o8   = lane & 7;    // which 16B chunk of the 128B row
    if (c >= n_nodes) return;
    int beg = offsets[c];
    int end = offsets[c + 1];
    int deg = end - beg;
    float a[8];
    #pragma unroll
    for (int k = 0; k < 8; ++k) a[k] = 0.0f;

    if (deg > 0) {
        int n1 = deg < 64 ? deg : 64;
        int ng = (n1 + 7) >> 3;        // active groups (wave-uniform)
        int rr[8];
        #pragma unroll
        for (int g = 0; g < 8; ++g) {
            int s = g * 8 + oct;
            if (g < ng) {
                int r = csr_rows[beg + (s < n1 ? s : 0)];
                rr[g] = (s < n1) ? r : n_nodes;      // zero row for tail
            } else {
                rr[g] = n_nodes;
            }
        }
        uint4 q[8];
        #pragma unroll
        for (int g = 0; g < 8; ++g)
            if (g < ng)
                q[g] = *(const uint4*)(zin + (size_t)rr[g] * EMB + o8 * 8);
        #pragma unroll
        for (int g = 0; g < 8; ++g) {
            if (g < ng) {
                acc2h(q[g].x, a[0], a[1]);
                acc2h(q[g].y, a[2], a[3]);
                acc2h(q[g].z, a[4], a[5]);
                acc2h(q[g].w, a[6], a[7]);
            }
        }
        // rare tail: deg > 64
        for (int j = beg + 64; j < end; j += 16) {
            int j0 = j + oct;
            int j1 = j + 8 + oct;
            bool v0 = j0 < end;
            bool v1 = j1 < end;
            int r0 = csr_rows[v0 ? j0 : beg]; r0 = v0 ? r0 : n_nodes;
            int r1 = csr_rows[v1 ? j1 : beg]; r1 = v1 ? r1 : n_nodes;
            uint4 q0 = *(const uint4*)(zin + (size_t)r0 * EMB + o8 * 8);
            uint4 q1 = *(const uint4*)(zin + (size_t)r1 * EMB + o8 * 8);
            acc2h(q0.x, a[0], a[1]);
            acc2h(q0.y, a[2], a[3]);
            acc2h(q0.z, a[4], a[5]);
            acc2h(q0.w, a[6], a[7]);
            acc2h(q1.x, a[0], a[1]);
            acc2h(q1.y, a[2], a[3]);
            acc2h(q1.z, a[4], a[5]);
            acc2h(q1.w, a[6], a[7]);
        }
    }

    #pragma unroll
    for (int k = 0; k < 8; ++k) {
        a[k] += __shfl_xor(a[k], 8, 64);
        a[k] += __shfl_xor(a[k], 16, 64);
        a[k] += __shfl_xor(a[k], 32, 64);
    }

    if (oct == 0) {   // lanes 0..7; lane l holds dims [8*l, 8*l+8)
        float dc = dis[c];
        float s2 = dc * dc;               // z_new = dis^2 * sum
        size_t fo = (size_t)c * EMB + o8 * 8;
        uint4 s;
        s.x = ((uint)f2h(s2 * a[1]) << 16) | f2h(s2 * a[0]);
        s.y = ((uint)f2h(s2 * a[3]) << 16) | f2h(s2 * a[2]);
        s.z = ((uint)f2h(s2 * a[5]) << 16) | f2h(s2 * a[4]);
        s.w = ((uint)f2h(s2 * a[7]) << 16) | f2h(s2 * a[6]);
        *(uint4*)(zout + fo) = s;
    }
}

// final: out = 0.25*x + (0.25/dis)*(z1+z2+z3); 8 elems per thread.
__global__ void lgcn_final_kernel(const float* __restrict__ user_w,
                                  const float* __restrict__ item_w,
                                  const float* __restrict__ dis,
                                  const ushort* __restrict__ z1,
                                  const ushort* __restrict__ z2,
                                  const ushort* __restrict__ z3,
                                  float* __restrict__ out,
                                  int n_user_elems, int n_total_elems) {
    int i8 = blockIdx.x * blockDim.x + threadIdx.x;
    int base = i8 << 3;
    if (base >= n_total_elems) return;
    int node = base >> 6;
    float dc = dis[node];
    float inv = (dc > 0.0f) ? 0.25f / dc : 0.0f;
    uint4 a = *(const uint4*)(z1 + base);
    uint4 b = *(const uint4*)(z2 + base);
    uint4 c = *(const uint4*)(z3 + base);
    float s[8];
    {
        float2 p, q, r;
        p = h2f2(a.x); q = h2f2(b.x); r = h2f2(c.x);
        s[0] = p.x + q.x + r.x; s[1] = p.y + q.y + r.y;
        p = h2f2(a.y); q = h2f2(b.y); r = h2f2(c.y);
        s[2] = p.x + q.x + r.x; s[3] = p.y + q.y + r.y;
        p = h2f2(a.z); q = h2f2(b.z); r = h2f2(c.z);
        s[4] = p.x + q.x + r.x; s[5] = p.y + q.y + r.y;
        p = h2f2(a.w); q = h2f2(b.w); r = h2f2(c.w);
        s[6] = p.x + q.x + r.x; s[7] = p.y + q.y + r.y;
    }
    float4 x0, x1;
    if (base < n_user_elems) {
        x0 = *(const float4*)(user_w + base);
        x1 = *(const float4*)(user_w + base + 4);
    } else {
        int j = base - n_user_elems;
        x0 = *(const float4*)(item_w + j);
        x1 = *(const float4*)(item_w + j + 4);
    }
    float4 o0, o1;
    o0.x = 0.25f * x0.x + inv * s[0];
    o0.y = 0.25f * x0.y + inv * s[1];
    o0.z = 0.25f * x0.z + inv * s[2];
    o0.w = 0.25f * x0.w + inv * s[3];
    o1.x = 0.25f * x1.x + inv * s[4];
    o1.y = 0.25f * x1.y + inv * s[5];
    o1.z = 0.25f * x1.z + inv * s[6];
    o1.w = 0.25f * x1.w + inv * s[7];
    *(float4*)(out + base) = o0;
    *(float4*)(out + base + 4) = o1;
}

extern "C" void kernel_launch(void* const* d_in, const int* in_sizes, int n_in,
                              void* d_out, int out_size, void* d_ws, size_t ws_size,
                              hipStream_t stream) {
    // ---- role assignment by element count ----
    int ie = 0, iu = 1, ii = 2;
    {
        long long s[3] = { in_sizes[0], in_sizes[1], in_sizes[2] };
        ie = 0;
        if (s[1] > s[ie]) ie = 1;
        if (s[2] > s[ie]) ie = 2;
        int rest[2], k = 0;
        for (int j = 0; j < 3; ++j) if (j != ie) rest[k++] = j;
        if (s[rest[0]] >= s[rest[1]]) { iu = rest[0]; ii = rest[1]; }
        else                          { iu = rest[1]; ii = rest[0]; }
    }
    const int*   edge_index = (const int*)d_in[ie];
    const float* user_w     = (const float*)d_in[iu];
    const float* item_w     = (const float*)d_in[ii];
    float* out = (float*)d_out;

    const int n_edges = in_sizes[ie] / 2;
    const int n_users = in_sizes[iu] / EMB;
    const int n_items = in_sizes[ii] / EMB;
    const int n_nodes = n_users + n_items;
    const int n_elems = n_nodes * EMB;
    const int NB = (n_nodes + BNODES - 1) / BNODES;   // 1172

    // ---- workspace carve (~93 MB; z3 aliases dead `pairs`) ----
    // fp16 state buffers each have one extra zero row at node index n_nodes.
    auto align_up = [](size_t x) { return (x + 1023) & ~(size_t)1023; };
    char* w = (char*)d_ws;
    int*   flag       = (int*)w; w += 1024;
    int*   bcount     = (int*)w; w += align_up((size_t)NB * sizeof(int));
    int*   bucketBase = (int*)w; w += align_up(((size_t)NB + 1) * sizeof(int));
    int*   bcur       = (int*)w; w += align_up((size_t)NB * sizeof(int));
    int*   offsets    = (int*)w; w += align_up(((size_t)n_nodes + 1) * sizeof(int));
    float* dis        = (float*)w; w += align_up((size_t)n_nodes * sizeof(float));
    int*   csr_rows   = (int*)w; w += align_up((size_t)n_edges * sizeof(int));
    size_t u_bytes = align_up(((size_t)n_elems + EMB) * sizeof(ushort));
    size_t p_bytes = align_up((size_t)n_edges * sizeof(uint));
    size_t slot0   = (u_bytes > p_bytes ? u_bytes : p_bytes);
    uint*   pairs = (uint*)w;
    ushort* z3    = (ushort*)w; w += slot0;      // z3 overlays dead pairs
    ushort* z0    = (ushort*)w; w += u_bytes;
    ushort* z1    = (ushort*)w; w += u_bytes;
    ushort* z2    = (ushort*)w; w += u_bytes;

    // 0) setup: dtype detect + zero counters + zero dummy rows
    lgcn_setup_kernel<<<1, 256, 0, stream>>>(edge_index, flag, bcount, bcur,
                                             z0, z1, z2, z3, NB, n_elems);

    // 1) bucket histogram -> scan -> staged scatter -> bucket CSR(+init)
    lgcn_bhist_kernel<<<(n_edges + 4095) / 4096, 256, 0, stream>>>(
        edge_index, flag, bcount, n_edges, n_nodes, NB);
    lgcn_bscan_kernel<<<1, 256, 0, stream>>>(bcount, bucketBase, offsets, NB, n_nodes);
    lgcn_bscatter3_kernel<<<(n_edges + CH - 1) / CH, STH, 0, stream>>>(
        edge_index, flag, bucketBase, bcur, pairs, n_edges, n_nodes, NB);
    lgcn_bcsr_kernel<<<NB, 256, 0, stream>>>(
        pairs, bucketBase, user_w, item_w, offsets, csr_rows, dis, z0,
        n_users * EMB, n_nodes);

    // 2) 3 pull layers: z0 -> z1 -> z2 -> z3 (z writes only, no total)
    {
        const int BLK = 256;
        long long n_thr = (long long)n_nodes * 64;
        int gW = (int)((n_thr + BLK - 1) / BLK);
        lgcn_gather_kernel<<<gW, BLK, 0, stream>>>(
            csr_rows, offsets, dis, z0, z1, n_nodes);
        lgcn_gather_kernel<<<gW, BLK, 0, stream>>>(
            csr_rows, offsets, dis, z1, z2, n_nodes);
        lgcn_gather_kernel<<<gW, BLK, 0, stream>>>(
            csr_rows, offsets, dis, z2, z3, n_nodes);
    }

    // 3) final: out = 0.25*x + (0.25/dis)*(z1+z2+z3)
    {
        const int BLK = 256;
        int nthr = n_elems / 8;
        lgcn_final_kernel<<<(nthr + BLK - 1) / BLK, BLK, 0, stream>>>(
            user_w, item_w, dis, z1, z2, z3, out, n_users * EMB, n_elems);
    }
}

// Round 5
// 426.455 us; speedup vs baseline: 1.3286x; 1.0177x over previous
//
#include <hip/hip_runtime.h>
#include <hip/hip_fp16.h>

// LightGCN on MI355X — block-aggregated bucket build + batched-MLP gather,
// deferred-total fp16 pipeline.
//
// Build: LDS bucket histogram -> scan -> block-aggregated pair scatter ->
// per-bucket LDS CSR finalize.
// R9:  bscatter 1024thr/CH=16384 (566->512).
// R10: batched 64-entry adjacency read + dis folded into state (512->481).
// R11: total deferred out of gathers; fp16 state; final pass (481->459).
// R12: bscatter pairs staged in LDS grouped by bucket, written
//      run-contiguously (459->434).
// R13: gather FETCH is within ~27% of the compulsory floor (8 XCDs x 19.2MB
//      table + csr), so attack the other two axes: (a) packed float2
//      accumulation (v_pk_add_f32) to cut inner-loop VALU ~25% (VALUBusy
//      was 62%); (b) fuse the `final` pass into gather layer 3's epilogue
//      (z3 never materialized: -38MB traffic, -1 launch); (c) 128-thr
//      gather blocks for finer CU balance (occupancy 77%).

#ifndef EMB
#define EMB 64
#endif
#define BSHIFT 7                 // 128 nodes per bucket
#define BNODES (1 << BSHIFT)
#define NBMAX 1280               // LDS histogram capacity
#define CCAP 4800                // LDS pair-staging capacity per bucket
#define CH 16384                 // edges per bscatter block
#define STH 1024                 // bscatter threads per block

typedef unsigned int uint;
typedef unsigned short ushort;

static __device__ __forceinline__ ushort f2h(float f) {
    __half h = __float2half(f);
    return *(ushort*)&h;
}

// u = two packed fp16 -> accumulate into float2 (pairs pack to v_pk_add_f32).
static __device__ __forceinline__ void acc2p(uint u, float2& a) {
    __half2 h = *(__half2*)&u;
    float2 f = __half22float2(h);
    a.x += f.x;
    a.y += f.y;
}

static __device__ __forceinline__ float2 h2f2(uint u) {
    __half2 h = *(__half2*)&u;
    return __half22float2(h);
}

// ---- setup: dtype detect + zero bucket counters + zero dummy rows ----
__global__ void lgcn_setup_kernel(const int* __restrict__ ei,
                                  int* __restrict__ flag,
                                  int* __restrict__ bcount,
                                  int* __restrict__ bcur,
                                  ushort* __restrict__ z0,
                                  ushort* __restrict__ z1,
                                  ushort* __restrict__ z2,
                                  int NB, int n_elems) {
    __shared__ int any_nz;
    int t = threadIdx.x;
    if (t == 0) any_nz = 0;
    __syncthreads();
    if (t < 128 && ei[2 * t + 1] != 0) atomicOr(&any_nz, 1);
    for (int i = t; i < NB; i += 256) { bcount[i] = 0; bcur[i] = 0; }
    if (t < EMB) {
        z0[n_elems + t] = 0;
        z1[n_elems + t] = 0;
        z2[n_elems + t] = 0;
    }
    __syncthreads();
    if (t == 0) *flag = (any_nz == 0) ? 1 : 0;
}

static __device__ __forceinline__ int load_idx(const int* __restrict__ ei,
                                               long long elem, int is64,
                                               int n_nodes) {
    int v = is64 ? ei[elem << 1] : ei[elem];
    return min(max(v, 0), n_nodes - 1);
}

// ---- build step 1: bucket histogram (LDS-staged) ----
__global__ void lgcn_bhist_kernel(const int* __restrict__ ei,
                                  const int* __restrict__ flag,
                                  int* __restrict__ bcount,
                                  int n_edges, int n_nodes, int NB) {
    __shared__ int h[NBMAX];
    int t = threadIdx.x;
    int is64 = *flag;
    for (int i = t; i < NB; i += 256) h[i] = 0;
    __syncthreads();
    long long base = (long long)blockIdx.x * 4096 + t;
    #pragma unroll
    for (int k = 0; k < 16; ++k) {
        long long e = base + (long long)k * 256;
        if (e < n_edges) {
            int c = load_idx(ei, (long long)n_edges + e, is64, n_nodes);
            atomicAdd(&h[c >> BSHIFT], 1);
        }
    }
    __syncthreads();
    for (int i = t; i < NB; i += 256) {
        int v = h[i];
        if (v) atomicAdd(&bcount[i], v);
    }
}

// ---- build step 2: exclusive scan of bucket counts (single block) ----
__global__ void lgcn_bscan_kernel(const int* __restrict__ bcount,
                                  int* __restrict__ bucketBase,
                                  int* __restrict__ offsets,
                                  int NB, int n_nodes) {
    __shared__ int tsum[256];
    int t = threadIdx.x;
    int K = (NB + 255) / 256;
    int base = t * K;
    int s = 0;
    for (int k = 0; k < K; ++k) {
        int i = base + k;
        if (i < NB) s += bcount[i];
    }
    tsum[t] = s;
    __syncthreads();
    for (int off = 1; off < 256; off <<= 1) {
        int x = (t >= off) ? tsum[t - off] : 0;
        __syncthreads();
        tsum[t] += x;
        __syncthreads();
    }
    int run = tsum[t] - s;
    for (int k = 0; k < K; ++k) {
        int i = base + k;
        if (i < NB) { bucketBase[i] = run; run += bcount[i]; }
    }
    if (t == 255) {
        bucketBase[NB] = tsum[255];
        offsets[n_nodes] = tsum[255];
    }
}

// ---- build step 3: block-aggregated pair scatter, LDS-staged (R12) ----
__global__ void __launch_bounds__(STH)
lgcn_bscatter3_kernel(const int* __restrict__ ei,
                      const int* __restrict__ flag,
                      const int* __restrict__ bucketBase,
                      int* __restrict__ bcur,
                      uint* __restrict__ pairs,
                      int n_edges, int n_nodes, int NB) {
    __shared__ int lcount[NBMAX];   // histogram, then staging cursor
    __shared__ int lloc[NBMAX];     // local staging base per bucket
    __shared__ int ldelta[NBMAX];   // global_run_base - local_base
    __shared__ int tsum[STH];
    __shared__ int ltot;
    __shared__ uint stage[CH];      // 64 KB pair staging
    __shared__ ushort stageb[CH];   // 32 KB bucket id per staged pair
    int t = threadIdx.x;
    int is64 = *flag;
    long long base = (long long)blockIdx.x * CH;
    for (int i = t; i < NB; i += STH) lcount[i] = 0;
    __syncthreads();
    // pass 1: local histogram of target buckets
    for (int k = t; k < CH; k += STH) {
        long long e = base + k;
        if (e < n_edges) {
            int c = load_idx(ei, (long long)n_edges + e, is64, n_nodes);
            atomicAdd(&lcount[c >> BSHIFT], 1);
        }
    }
    __syncthreads();
    // local exclusive scan lcount -> lloc (staging layout)
    {
        int K = (NB + STH - 1) / STH;
        int cbase = t * K;
        int s = 0;
        for (int k = 0; k < K; ++k) {
            int i = cbase + k;
            if (i < NB) s += lcount[i];
        }
        tsum[t] = s;
        __syncthreads();
        for (int off = 1; off < STH; off <<= 1) {
            int x = (t >= off) ? tsum[t - off] : 0;
            __syncthreads();
            tsum[t] += x;
            __syncthreads();
        }
        int run = tsum[t] - s;
        for (int k = 0; k < K; ++k) {
            int i = cbase + k;
            if (i < NB) { lloc[i] = run; run += lcount[i]; }
        }
        if (t == STH - 1) ltot = tsum[t];
    }
    __syncthreads();
    // reservation: one global atomic per non-empty bucket
    for (int i = t; i < NB; i += STH) {
        int cnt = lcount[i];
        ldelta[i] = cnt ? (bucketBase[i] + atomicAdd(&bcur[i], cnt) - lloc[i]) : 0;
        lcount[i] = 0;   // reuse as staging cursor
    }
    __syncthreads();
    // pass 2: stage pairs grouped by bucket in LDS
    for (int k = t; k < CH; k += STH) {
        long long e = base + k;
        if (e < n_edges) {
            int r = load_idx(ei, e, is64, n_nodes);
            int c = load_idx(ei, (long long)n_edges + e, is64, n_nodes);
            int b = c >> BSHIFT;
            int pos = lloc[b] + atomicAdd(&lcount[b], 1);
            stage[pos] = ((uint)r << BSHIFT) | (uint)(c & (BNODES - 1));
            stageb[pos] = (ushort)b;
        }
    }
    __syncthreads();
    // pass 3: coalesced run-contiguous global writes
    int tot = ltot;
    for (int k = t; k < tot; k += STH) {
        pairs[ldelta[stageb[k]] + k] = stage[k];
    }
}

// ---- build step 4: per-bucket CSR finalize + fused z0 init ----
__global__ void lgcn_bcsr_kernel(const uint* __restrict__ pairs,
                                 const int* __restrict__ bucketBase,
                                 const float* __restrict__ user_w,
                                 const float* __restrict__ item_w,
                                 int* __restrict__ offsets,
                                 int* __restrict__ csr_rows,
                                 float* __restrict__ dis,
                                 ushort* __restrict__ z0,
                                 int n_user_elems, int n_nodes) {
    __shared__ int deg[BNODES];
    __shared__ int tmp[BNODES];
    __shared__ int loffx[BNODES];
    __shared__ int cur[BNODES];
    __shared__ float disL[BNODES];
    __shared__ uint lp[CCAP];
    int b = blockIdx.x;
    int t = threadIdx.x;            // 256 threads
    int nodeStart = b << BSHIFT;
    int base = bucketBase[b];
    int span = bucketBase[b + 1] - base;
    bool fits = (span <= CCAP);
    if (t < BNODES) deg[t] = 0;
    __syncthreads();
    for (int i = t; i < span; i += 256) {
        uint p = pairs[base + i];
        if (fits) lp[i] = p;
        atomicAdd(&deg[p & (BNODES - 1)], 1);
    }
    __syncthreads();
    if (t < BNODES) tmp[t] = deg[t];
    __syncthreads();
    for (int off = 1; off < BNODES; off <<= 1) {
        int x = (t < BNODES && t >= off) ? tmp[t - off] : 0;
        __syncthreads();
        if (t < BNODES) tmp[t] += x;
        __syncthreads();
    }
    if (t < BNODES) {
        int excl = tmp[t] - deg[t];
        loffx[t] = excl;
        cur[t] = 0;
        float d = (deg[t] > 0) ? rsqrtf((float)deg[t]) : 0.0f;
        disL[t] = d;
        int node = nodeStart + t;
        if (node < n_nodes) {
            offsets[node] = base + excl;
            dis[node] = d;
        }
    }
    __syncthreads();
    for (int i = t; i < span; i += 256) {
        uint p = fits ? lp[i] : pairs[base + i];
        int cl = (int)(p & (BNODES - 1));
        int pos = loffx[cl] + atomicAdd(&cur[cl], 1);
        csr_rows[base + pos] = (int)(p >> BSHIFT);
    }
    // fused init: z0 rows for this bucket's nodes, z0 = fp16(dis * x)
    int eBase = nodeStart << 6;               // first element of this bucket
    for (int e4 = t; e4 < (BNODES << 4); e4 += 256) {   // float4 granules
        int e = e4 << 2;
        int node = nodeStart + (e >> 6);
        if (node < n_nodes) {
            int gi = eBase + e;
            float4 v = (gi < n_user_elems)
                ? *(const float4*)(user_w + gi)
                : *(const float4*)(item_w + (gi - n_user_elems));
            float d = disL[e >> 6];
            ushort4 o;
            o.x = f2h(d * v.x); o.y = f2h(d * v.y);
            o.z = f2h(d * v.z); o.w = f2h(d * v.w);
            *(ushort4*)(z0 + gi) = o;
        }
    }
}

// gather: one wave per node; 8 lanes per edge (uint4 = 16B per lane).
// State pre-scaled z = dis*acc (fp16): inner loop is csr -> row only.
// Up to 64 adjacency entries in one coalesced csr read; row gathers issued
// back-to-back. Accumulation in float2 pairs (packs to v_pk_add_f32).
// FUSE (layer 3): epilogue computes out = 0.25*(x + inv*(z1+z2) + dc*sum)
// directly — z3 never materialized.
template <bool FUSE>
__global__ void lgcn_gather_kernel(const int* __restrict__ csr_rows,
                                   const int* __restrict__ offsets,
                                   const float* __restrict__ dis,
                                   const ushort* __restrict__ zin,
                                   ushort* __restrict__ zout,
                                   const ushort* __restrict__ zprev,
                                   const float* __restrict__ user_w,
                                   const float* __restrict__ item_w,
                                   float* __restrict__ out,
                                   int n_user_elems, int n_nodes) {
    long long tid = (long long)blockIdx.x * blockDim.x + threadIdx.x;
    int c    = (int)(tid >> 6);
    int lane = threadIdx.x & 63;
    int oct  = lane >> 3;   // edge slot 0..7 within a group
    int o8   = lane & 7;    // which 16B chunk of the 128B row
    if (c >= n_nodes) return;
    int beg = offsets[c];
    int end = offsets[c + 1];
    int deg = end - beg;
    float2 a0 = {0.f, 0.f}, a1 = {0.f, 0.f}, a2 = {0.f, 0.f}, a3 = {0.f, 0.f};

    if (deg > 0) {
        int n1 = deg < 64 ? deg : 64;
        int ng = (n1 + 7) >> 3;        // active groups (wave-uniform)
        int rr[8];
        #pragma unroll
        for (int g = 0; g < 8; ++g) {
            int s = g * 8 + oct;
            if (g < ng) {
                int r = csr_rows[beg + (s < n1 ? s : 0)];
                rr[g] = (s < n1) ? r : n_nodes;      // zero row for tail
            } else {
                rr[g] = n_nodes;
            }
        }
        uint4 q[8];
        #pragma unroll
        for (int g = 0; g < 8; ++g)
            if (g < ng)
                q[g] = *(const uint4*)(zin + (size_t)rr[g] * EMB + o8 * 8);
        #pragma unroll
        for (int g = 0; g < 8; ++g) {
            if (g < ng) {
                acc2p(q[g].x, a0);
                acc2p(q[g].y, a1);
                acc2p(q[g].z, a2);
                acc2p(q[g].w, a3);
            }
        }
        // rare tail: deg > 64
        for (int j = beg + 64; j < end; j += 16) {
            int j0 = j + oct;
            int j1 = j + 8 + oct;
            bool v0 = j0 < end;
            bool v1 = j1 < end;
            int r0 = csr_rows[v0 ? j0 : beg]; r0 = v0 ? r0 : n_nodes;
            int r1 = csr_rows[v1 ? j1 : beg]; r1 = v1 ? r1 : n_nodes;
            uint4 q0 = *(const uint4*)(zin + (size_t)r0 * EMB + o8 * 8);
            uint4 q1 = *(const uint4*)(zin + (size_t)r1 * EMB + o8 * 8);
            acc2p(q0.x, a0); acc2p(q0.y, a1);
            acc2p(q0.z, a2); acc2p(q0.w, a3);
            acc2p(q1.x, a0); acc2p(q1.y, a1);
            acc2p(q1.z, a2); acc2p(q1.w, a3);
        }
    }

    float s[8] = { a0.x, a0.y, a1.x, a1.y, a2.x, a2.y, a3.x, a3.y };
    #pragma unroll
    for (int k = 0; k < 8; ++k) {
        s[k] += __shfl_xor(s[k], 8, 64);
        s[k] += __shfl_xor(s[k], 16, 64);
        s[k] += __shfl_xor(s[k], 32, 64);
    }

    if (oct == 0) {   // lanes 0..7; lane l holds dims [8*l, 8*l+8)
        float dc = dis[c];
        size_t fo = (size_t)c * EMB + o8 * 8;
        if (!FUSE) {
            float s2 = dc * dc;               // z_new = dis^2 * sum
            uint4 v;
            v.x = ((uint)f2h(s2 * s[1]) << 16) | f2h(s2 * s[0]);
            v.y = ((uint)f2h(s2 * s[3]) << 16) | f2h(s2 * s[2]);
            v.z = ((uint)f2h(s2 * s[5]) << 16) | f2h(s2 * s[4]);
            v.w = ((uint)f2h(s2 * s[7]) << 16) | f2h(s2 * s[6]);
            *(uint4*)(zout + fo) = v;
        } else {
            // out = 0.25*(x + inv*(z1+z2) + dc*sum); inv = 1/dc (0 if deg=0)
            float inv = (dc > 0.0f) ? 1.0f / dc : 0.0f;
            uint4 v1 = *(const uint4*)(zprev + fo);
            uint4 v2 = *(const uint4*)(zin + fo);
            float4 x0, x1;
            if ((int)fo < n_user_elems) {
                x0 = *(const float4*)(user_w + fo);
                x1 = *(const float4*)(user_w + fo + 4);
            } else {
                size_t j = fo - n_user_elems;
                x0 = *(const float4*)(item_w + j);
                x1 = *(const float4*)(item_w + j + 4);
            }
            float2 p, q;
            float4 o0, o1;
            p = h2f2(v1.x); q = h2f2(v2.x);
            o0.x = 0.25f * (x0.x + inv * (p.x + q.x) + dc * s[0]);
            o0.y = 0.25f * (x0.y + inv * (p.y + q.y) + dc * s[1]);
            p = h2f2(v1.y); q = h2f2(v2.y);
            o0.z = 0.25f * (x0.z + inv * (p.x + q.x) + dc * s[2]);
            o0.w = 0.25f * (x0.w + inv * (p.y + q.y) + dc * s[3]);
            p = h2f2(v1.z); q = h2f2(v2.z);
            o1.x = 0.25f * (x1.x + inv * (p.x + q.x) + dc * s[4]);
            o1.y = 0.25f * (x1.y + inv * (p.y + q.y) + dc * s[5]);
            p = h2f2(v1.w); q = h2f2(v2.w);
            o1.z = 0.25f * (x1.z + inv * (p.x + q.x) + dc * s[6]);
            o1.w = 0.25f * (x1.w + inv * (p.y + q.y) + dc * s[7]);
            *(float4*)(out + fo) = o0;
            *(float4*)(out + fo + 4) = o1;
        }
    }
}

extern "C" void kernel_launch(void* const* d_in, const int* in_sizes, int n_in,
                              void* d_out, int out_size, void* d_ws, size_t ws_size,
                              hipStream_t stream) {
    // ---- role assignment by element count ----
    int ie = 0, iu = 1, ii = 2;
    {
        long long s[3] = { in_sizes[0], in_sizes[1], in_sizes[2] };
        ie = 0;
        if (s[1] > s[ie]) ie = 1;
        if (s[2] > s[ie]) ie = 2;
        int rest[2], k = 0;
        for (int j = 0; j < 3; ++j) if (j != ie) rest[k++] = j;
        if (s[rest[0]] >= s[rest[1]]) { iu = rest[0]; ii = rest[1]; }
        else                          { iu = rest[1]; ii = rest[0]; }
    }
    const int*   edge_index = (const int*)d_in[ie];
    const float* user_w     = (const float*)d_in[iu];
    const float* item_w     = (const float*)d_in[ii];
    float* out = (float*)d_out;

    const int n_edges = in_sizes[ie] / 2;
    const int n_users = in_sizes[iu] / EMB;
    const int n_items = in_sizes[ii] / EMB;
    const int n_nodes = n_users + n_items;
    const int n_elems = n_nodes * EMB;
    const int NB = (n_nodes + BNODES - 1) / BNODES;   // 1172

    // ---- workspace carve (~90 MB) ----
    // fp16 state buffers each have one extra zero row at node index n_nodes.
    auto align_up = [](size_t x) { return (x + 1023) & ~(size_t)1023; };
    char* w = (char*)d_ws;
    int*   flag       = (int*)w; w += 1024;
    int*   bcount     = (int*)w; w += align_up((size_t)NB * sizeof(int));
    int*   bucketBase = (int*)w; w += align_up(((size_t)NB + 1) * sizeof(int));
    int*   bcur       = (int*)w; w += align_up((size_t)NB * sizeof(int));
    int*   offsets    = (int*)w; w += align_up(((size_t)n_nodes + 1) * sizeof(int));
    float* dis        = (float*)w; w += align_up((size_t)n_nodes * sizeof(float));
    int*   csr_rows   = (int*)w; w += align_up((size_t)n_edges * sizeof(int));
    size_t u_bytes = align_up(((size_t)n_elems + EMB) * sizeof(ushort));
    size_t p_bytes = align_up((size_t)n_edges * sizeof(uint));
    uint*   pairs = (uint*)w; w += p_bytes;
    ushort* z0    = (ushort*)w; w += u_bytes;
    ushort* z1    = (ushort*)w; w += u_bytes;
    ushort* z2    = (ushort*)w; w += u_bytes;

    // 0) setup: dtype detect + zero counters + zero dummy rows
    lgcn_setup_kernel<<<1, 256, 0, stream>>>(edge_index, flag, bcount, bcur,
                                             z0, z1, z2, NB, n_elems);

    // 1) bucket histogram -> scan -> staged scatter -> bucket CSR(+init)
    lgcn_bhist_kernel<<<(n_edges + 4095) / 4096, 256, 0, stream>>>(
        edge_index, flag, bcount, n_edges, n_nodes, NB);
    lgcn_bscan_kernel<<<1, 256, 0, stream>>>(bcount, bucketBase, offsets, NB, n_nodes);
    lgcn_bscatter3_kernel<<<(n_edges + CH - 1) / CH, STH, 0, stream>>>(
        edge_index, flag, bucketBase, bcur, pairs, n_edges, n_nodes, NB);
    lgcn_bcsr_kernel<<<NB, 256, 0, stream>>>(
        pairs, bucketBase, user_w, item_w, offsets, csr_rows, dis, z0,
        n_users * EMB, n_nodes);

    // 2) 3 pull layers: z0 -> z1 -> z2 -> (fused) out
    {
        const int BLK = 128;
        long long n_thr = (long long)n_nodes * 64;
        int gW = (int)((n_thr + BLK - 1) / BLK);
        lgcn_gather_kernel<false><<<gW, BLK, 0, stream>>>(
            csr_rows, offsets, dis, z0, z1,
            nullptr, nullptr, nullptr, nullptr, 0, n_nodes);
        lgcn_gather_kernel<false><<<gW, BLK, 0, stream>>>(
            csr_rows, offsets, dis, z1, z2,
            nullptr, nullptr, nullptr, nullptr, 0, n_nodes);
        lgcn_gather_kernel<true><<<gW, BLK, 0, stream>>>(
            csr_rows, offsets, dis, z2, nullptr,
            z1, user_w, item_w, out, n_users * EMB, n_nodes);
    }
}

// Round 6
// 424.329 us; speedup vs baseline: 1.3353x; 1.0050x over previous
//
#include <hip/hip_runtime.h>
#include <hip/hip_fp16.h>

// LightGCN on MI355X — block-aggregated bucket build + batched-MLP gather,
// deferred-total fp16 pipeline.
//
// Build: LDS bucket histogram -> scan -> block-aggregated pair scatter ->
// per-bucket LDS CSR finalize.
// R9:  bscatter 1024thr/CH=16384 (566->512).
// R10: batched 64-entry adjacency read + dis folded into state (512->481).
// R11: total deferred out of gathers; fp16 state; final pass (481->459).
// R12: bscatter pairs staged in LDS grouped by bucket, written
//      run-contiguously (459->434).
// R13: fused final into gather layer 3 (WIN, kept); packed float2 acc
//      (neutral, kept); BLK 128 (REGRESSION: FETCH 217->261MB, g 74->86us
//      — finer block granularity broke node->XCD L2 locality).
// R14: gather blocks back to 256 threads (4 nodes/block share L1/L2
//      window). Single-variable revert; fusion + float2 kept.

#ifndef EMB
#define EMB 64
#endif
#define BSHIFT 7                 // 128 nodes per bucket
#define BNODES (1 << BSHIFT)
#define NBMAX 1280               // LDS histogram capacity
#define CCAP 4800                // LDS pair-staging capacity per bucket
#define CH 16384                 // edges per bscatter block
#define STH 1024                 // bscatter threads per block

typedef unsigned int uint;
typedef unsigned short ushort;

static __device__ __forceinline__ ushort f2h(float f) {
    __half h = __float2half(f);
    return *(ushort*)&h;
}

// u = two packed fp16 -> accumulate into float2 (pairs pack to v_pk_add_f32).
static __device__ __forceinline__ void acc2p(uint u, float2& a) {
    __half2 h = *(__half2*)&u;
    float2 f = __half22float2(h);
    a.x += f.x;
    a.y += f.y;
}

static __device__ __forceinline__ float2 h2f2(uint u) {
    __half2 h = *(__half2*)&u;
    return __half22float2(h);
}

// ---- setup: dtype detect + zero bucket counters + zero dummy rows ----
__global__ void lgcn_setup_kernel(const int* __restrict__ ei,
                                  int* __restrict__ flag,
                                  int* __restrict__ bcount,
                                  int* __restrict__ bcur,
                                  ushort* __restrict__ z0,
                                  ushort* __restrict__ z1,
                                  ushort* __restrict__ z2,
                                  int NB, int n_elems) {
    __shared__ int any_nz;
    int t = threadIdx.x;
    if (t == 0) any_nz = 0;
    __syncthreads();
    if (t < 128 && ei[2 * t + 1] != 0) atomicOr(&any_nz, 1);
    for (int i = t; i < NB; i += 256) { bcount[i] = 0; bcur[i] = 0; }
    if (t < EMB) {
        z0[n_elems + t] = 0;
        z1[n_elems + t] = 0;
        z2[n_elems + t] = 0;
    }
    __syncthreads();
    if (t == 0) *flag = (any_nz == 0) ? 1 : 0;
}

static __device__ __forceinline__ int load_idx(const int* __restrict__ ei,
                                               long long elem, int is64,
                                               int n_nodes) {
    int v = is64 ? ei[elem << 1] : ei[elem];
    return min(max(v, 0), n_nodes - 1);
}

// ---- build step 1: bucket histogram (LDS-staged) ----
__global__ void lgcn_bhist_kernel(const int* __restrict__ ei,
                                  const int* __restrict__ flag,
                                  int* __restrict__ bcount,
                                  int n_edges, int n_nodes, int NB) {
    __shared__ int h[NBMAX];
    int t = threadIdx.x;
    int is64 = *flag;
    for (int i = t; i < NB; i += 256) h[i] = 0;
    __syncthreads();
    long long base = (long long)blockIdx.x * 4096 + t;
    #pragma unroll
    for (int k = 0; k < 16; ++k) {
        long long e = base + (long long)k * 256;
        if (e < n_edges) {
            int c = load_idx(ei, (long long)n_edges + e, is64, n_nodes);
            atomicAdd(&h[c >> BSHIFT], 1);
        }
    }
    __syncthreads();
    for (int i = t; i < NB; i += 256) {
        int v = h[i];
        if (v) atomicAdd(&bcount[i], v);
    }
}

// ---- build step 2: exclusive scan of bucket counts (single block) ----
__global__ void lgcn_bscan_kernel(const int* __restrict__ bcount,
                                  int* __restrict__ bucketBase,
                                  int* __restrict__ offsets,
                                  int NB, int n_nodes) {
    __shared__ int tsum[256];
    int t = threadIdx.x;
    int K = (NB + 255) / 256;
    int base = t * K;
    int s = 0;
    for (int k = 0; k < K; ++k) {
        int i = base + k;
        if (i < NB) s += bcount[i];
    }
    tsum[t] = s;
    __syncthreads();
    for (int off = 1; off < 256; off <<= 1) {
        int x = (t >= off) ? tsum[t - off] : 0;
        __syncthreads();
        tsum[t] += x;
        __syncthreads();
    }
    int run = tsum[t] - s;
    for (int k = 0; k < K; ++k) {
        int i = base + k;
        if (i < NB) { bucketBase[i] = run; run += bcount[i]; }
    }
    if (t == 255) {
        bucketBase[NB] = tsum[255];
        offsets[n_nodes] = tsum[255];
    }
}

// ---- build step 3: block-aggregated pair scatter, LDS-staged (R12) ----
__global__ void __launch_bounds__(STH)
lgcn_bscatter3_kernel(const int* __restrict__ ei,
                      const int* __restrict__ flag,
                      const int* __restrict__ bucketBase,
                      int* __restrict__ bcur,
                      uint* __restrict__ pairs,
                      int n_edges, int n_nodes, int NB) {
    __shared__ int lcount[NBMAX];   // histogram, then staging cursor
    __shared__ int lloc[NBMAX];     // local staging base per bucket
    __shared__ int ldelta[NBMAX];   // global_run_base - local_base
    __shared__ int tsum[STH];
    __shared__ int ltot;
    __shared__ uint stage[CH];      // 64 KB pair staging
    __shared__ ushort stageb[CH];   // 32 KB bucket id per staged pair
    int t = threadIdx.x;
    int is64 = *flag;
    long long base = (long long)blockIdx.x * CH;
    for (int i = t; i < NB; i += STH) lcount[i] = 0;
    __syncthreads();
    // pass 1: local histogram of target buckets
    for (int k = t; k < CH; k += STH) {
        long long e = base + k;
        if (e < n_edges) {
            int c = load_idx(ei, (long long)n_edges + e, is64, n_nodes);
            atomicAdd(&lcount[c >> BSHIFT], 1);
        }
    }
    __syncthreads();
    // local exclusive scan lcount -> lloc (staging layout)
    {
        int K = (NB + STH - 1) / STH;
        int cbase = t * K;
        int s = 0;
        for (int k = 0; k < K; ++k) {
            int i = cbase + k;
            if (i < NB) s += lcount[i];
        }
        tsum[t] = s;
        __syncthreads();
        for (int off = 1; off < STH; off <<= 1) {
            int x = (t >= off) ? tsum[t - off] : 0;
            __syncthreads();
            tsum[t] += x;
            __syncthreads();
        }
        int run = tsum[t] - s;
        for (int k = 0; k < K; ++k) {
            int i = cbase + k;
            if (i < NB) { lloc[i] = run; run += lcount[i]; }
        }
        if (t == STH - 1) ltot = tsum[t];
    }
    __syncthreads();
    // reservation: one global atomic per non-empty bucket
    for (int i = t; i < NB; i += STH) {
        int cnt = lcount[i];
        ldelta[i] = cnt ? (bucketBase[i] + atomicAdd(&bcur[i], cnt) - lloc[i]) : 0;
        lcount[i] = 0;   // reuse as staging cursor
    }
    __syncthreads();
    // pass 2: stage pairs grouped by bucket in LDS
    for (int k = t; k < CH; k += STH) {
        long long e = base + k;
        if (e < n_edges) {
            int r = load_idx(ei, e, is64, n_nodes);
            int c = load_idx(ei, (long long)n_edges + e, is64, n_nodes);
            int b = c >> BSHIFT;
            int pos = lloc[b] + atomicAdd(&lcount[b], 1);
            stage[pos] = ((uint)r << BSHIFT) | (uint)(c & (BNODES - 1));
            stageb[pos] = (ushort)b;
        }
    }
    __syncthreads();
    // pass 3: coalesced run-contiguous global writes
    int tot = ltot;
    for (int k = t; k < tot; k += STH) {
        pairs[ldelta[stageb[k]] + k] = stage[k];
    }
}

// ---- build step 4: per-bucket CSR finalize + fused z0 init ----
__global__ void lgcn_bcsr_kernel(const uint* __restrict__ pairs,
                                 const int* __restrict__ bucketBase,
                                 const float* __restrict__ user_w,
                                 const float* __restrict__ item_w,
                                 int* __restrict__ offsets,
                                 int* __restrict__ csr_rows,
                                 float* __restrict__ dis,
                                 ushort* __restrict__ z0,
                                 int n_user_elems, int n_nodes) {
    __shared__ int deg[BNODES];
    __shared__ int tmp[BNODES];
    __shared__ int loffx[BNODES];
    __shared__ int cur[BNODES];
    __shared__ float disL[BNODES];
    __shared__ uint lp[CCAP];
    int b = blockIdx.x;
    int t = threadIdx.x;            // 256 threads
    int nodeStart = b << BSHIFT;
    int base = bucketBase[b];
    int span = bucketBase[b + 1] - base;
    bool fits = (span <= CCAP);
    if (t < BNODES) deg[t] = 0;
    __syncthreads();
    for (int i = t; i < span; i += 256) {
        uint p = pairs[base + i];
        if (fits) lp[i] = p;
        atomicAdd(&deg[p & (BNODES - 1)], 1);
    }
    __syncthreads();
    if (t < BNODES) tmp[t] = deg[t];
    __syncthreads();
    for (int off = 1; off < BNODES; off <<= 1) {
        int x = (t < BNODES && t >= off) ? tmp[t - off] : 0;
        __syncthreads();
        if (t < BNODES) tmp[t] += x;
        __syncthreads();
    }
    if (t < BNODES) {
        int excl = tmp[t] - deg[t];
        loffx[t] = excl;
        cur[t] = 0;
        float d = (deg[t] > 0) ? rsqrtf((float)deg[t]) : 0.0f;
        disL[t] = d;
        int node = nodeStart + t;
        if (node < n_nodes) {
            offsets[node] = base + excl;
            dis[node] = d;
        }
    }
    __syncthreads();
    for (int i = t; i < span; i += 256) {
        uint p = fits ? lp[i] : pairs[base + i];
        int cl = (int)(p & (BNODES - 1));
        int pos = loffx[cl] + atomicAdd(&cur[cl], 1);
        csr_rows[base + pos] = (int)(p >> BSHIFT);
    }
    // fused init: z0 rows for this bucket's nodes, z0 = fp16(dis * x)
    int eBase = nodeStart << 6;               // first element of this bucket
    for (int e4 = t; e4 < (BNODES << 4); e4 += 256) {   // float4 granules
        int e = e4 << 2;
        int node = nodeStart + (e >> 6);
        if (node < n_nodes) {
            int gi = eBase + e;
            float4 v = (gi < n_user_elems)
                ? *(const float4*)(user_w + gi)
                : *(const float4*)(item_w + (gi - n_user_elems));
            float d = disL[e >> 6];
            ushort4 o;
            o.x = f2h(d * v.x); o.y = f2h(d * v.y);
            o.z = f2h(d * v.z); o.w = f2h(d * v.w);
            *(ushort4*)(z0 + gi) = o;
        }
    }
}

// gather: one wave per node; 8 lanes per edge (uint4 = 16B per lane).
// State pre-scaled z = dis*acc (fp16): inner loop is csr -> row only.
// Up to 64 adjacency entries in one coalesced csr read; row gathers issued
// back-to-back. Accumulation in float2 pairs (packs to v_pk_add_f32).
// FUSE (layer 3): epilogue computes out = 0.25*(x + inv*(z1+z2) + dc*sum)
// directly — z3 never materialized.
template <bool FUSE>
__global__ void lgcn_gather_kernel(const int* __restrict__ csr_rows,
                                   const int* __restrict__ offsets,
                                   const float* __restrict__ dis,
                                   const ushort* __restrict__ zin,
                                   ushort* __restrict__ zout,
                                   const ushort* __restrict__ zprev,
                                   const float* __restrict__ user_w,
                                   const float* __restrict__ item_w,
                                   float* __restrict__ out,
                                   int n_user_elems, int n_nodes) {
    long long tid = (long long)blockIdx.x * blockDim.x + threadIdx.x;
    int c    = (int)(tid >> 6);
    int lane = threadIdx.x & 63;
    int oct  = lane >> 3;   // edge slot 0..7 within a group
    int o8   = lane & 7;    // which 16B chunk of the 128B row
    if (c >= n_nodes) return;
    int beg = offsets[c];
    int end = offsets[c + 1];
    int deg = end - beg;
    float2 a0 = {0.f, 0.f}, a1 = {0.f, 0.f}, a2 = {0.f, 0.f}, a3 = {0.f, 0.f};

    if (deg > 0) {
        int n1 = deg < 64 ? deg : 64;
        int ng = (n1 + 7) >> 3;        // active groups (wave-uniform)
        int rr[8];
        #pragma unroll
        for (int g = 0; g < 8; ++g) {
            int s = g * 8 + oct;
            if (g < ng) {
                int r = csr_rows[beg + (s < n1 ? s : 0)];
                rr[g] = (s < n1) ? r : n_nodes;      // zero row for tail
            } else {
                rr[g] = n_nodes;
            }
        }
        uint4 q[8];
        #pragma unroll
        for (int g = 0; g < 8; ++g)
            if (g < ng)
                q[g] = *(const uint4*)(zin + (size_t)rr[g] * EMB + o8 * 8);
        #pragma unroll
        for (int g = 0; g < 8; ++g) {
            if (g < ng) {
                acc2p(q[g].x, a0);
                acc2p(q[g].y, a1);
                acc2p(q[g].z, a2);
                acc2p(q[g].w, a3);
            }
        }
        // rare tail: deg > 64
        for (int j = beg + 64; j < end; j += 16) {
            int j0 = j + oct;
            int j1 = j + 8 + oct;
            bool v0 = j0 < end;
            bool v1 = j1 < end;
            int r0 = csr_rows[v0 ? j0 : beg]; r0 = v0 ? r0 : n_nodes;
            int r1 = csr_rows[v1 ? j1 : beg]; r1 = v1 ? r1 : n_nodes;
            uint4 q0 = *(const uint4*)(zin + (size_t)r0 * EMB + o8 * 8);
            uint4 q1 = *(const uint4*)(zin + (size_t)r1 * EMB + o8 * 8);
            acc2p(q0.x, a0); acc2p(q0.y, a1);
            acc2p(q0.z, a2); acc2p(q0.w, a3);
            acc2p(q1.x, a0); acc2p(q1.y, a1);
            acc2p(q1.z, a2); acc2p(q1.w, a3);
        }
    }

    float s[8] = { a0.x, a0.y, a1.x, a1.y, a2.x, a2.y, a3.x, a3.y };
    #pragma unroll
    for (int k = 0; k < 8; ++k) {
        s[k] += __shfl_xor(s[k], 8, 64);
        s[k] += __shfl_xor(s[k], 16, 64);
        s[k] += __shfl_xor(s[k], 32, 64);
    }

    if (oct == 0) {   // lanes 0..7; lane l holds dims [8*l, 8*l+8)
        float dc = dis[c];
        size_t fo = (size_t)c * EMB + o8 * 8;
        if (!FUSE) {
            float s2 = dc * dc;               // z_new = dis^2 * sum
            uint4 v;
            v.x = ((uint)f2h(s2 * s[1]) << 16) | f2h(s2 * s[0]);
            v.y = ((uint)f2h(s2 * s[3]) << 16) | f2h(s2 * s[2]);
            v.z = ((uint)f2h(s2 * s[5]) << 16) | f2h(s2 * s[4]);
            v.w = ((uint)f2h(s2 * s[7]) << 16) | f2h(s2 * s[6]);
            *(uint4*)(zout + fo) = v;
        } else {
            // out = 0.25*(x + inv*(z1+z2) + dc*sum); inv = 1/dc (0 if deg=0)
            float inv = (dc > 0.0f) ? 1.0f / dc : 0.0f;
            uint4 v1 = *(const uint4*)(zprev + fo);
            uint4 v2 = *(const uint4*)(zin + fo);
            float4 x0, x1;
            if ((int)fo < n_user_elems) {
                x0 = *(const float4*)(user_w + fo);
                x1 = *(const float4*)(user_w + fo + 4);
            } else {
                size_t j = fo - n_user_elems;
                x0 = *(const float4*)(item_w + j);
                x1 = *(const float4*)(item_w + j + 4);
            }
            float2 p, q;
            float4 o0, o1;
            p = h2f2(v1.x); q = h2f2(v2.x);
            o0.x = 0.25f * (x0.x + inv * (p.x + q.x) + dc * s[0]);
            o0.y = 0.25f * (x0.y + inv * (p.y + q.y) + dc * s[1]);
            p = h2f2(v1.y); q = h2f2(v2.y);
            o0.z = 0.25f * (x0.z + inv * (p.x + q.x) + dc * s[2]);
            o0.w = 0.25f * (x0.w + inv * (p.y + q.y) + dc * s[3]);
            p = h2f2(v1.z); q = h2f2(v2.z);
            o1.x = 0.25f * (x1.x + inv * (p.x + q.x) + dc * s[4]);
            o1.y = 0.25f * (x1.y + inv * (p.y + q.y) + dc * s[5]);
            p = h2f2(v1.w); q = h2f2(v2.w);
            o1.z = 0.25f * (x1.z + inv * (p.x + q.x) + dc * s[6]);
            o1.w = 0.25f * (x1.w + inv * (p.y + q.y) + dc * s[7]);
            *(float4*)(out + fo) = o0;
            *(float4*)(out + fo + 4) = o1;
        }
    }
}

extern "C" void kernel_launch(void* const* d_in, const int* in_sizes, int n_in,
                              void* d_out, int out_size, void* d_ws, size_t ws_size,
                              hipStream_t stream) {
    // ---- role assignment by element count ----
    int ie = 0, iu = 1, ii = 2;
    {
        long long s[3] = { in_sizes[0], in_sizes[1], in_sizes[2] };
        ie = 0;
        if (s[1] > s[ie]) ie = 1;
        if (s[2] > s[ie]) ie = 2;
        int rest[2], k = 0;
        for (int j = 0; j < 3; ++j) if (j != ie) rest[k++] = j;
        if (s[rest[0]] >= s[rest[1]]) { iu = rest[0]; ii = rest[1]; }
        else                          { iu = rest[1]; ii = rest[0]; }
    }
    const int*   edge_index = (const int*)d_in[ie];
    const float* user_w     = (const float*)d_in[iu];
    const float* item_w     = (const float*)d_in[ii];
    float* out = (float*)d_out;

    const int n_edges = in_sizes[ie] / 2;
    const int n_users = in_sizes[iu] / EMB;
    const int n_items = in_sizes[ii] / EMB;
    const int n_nodes = n_users + n_items;
    const int n_elems = n_nodes * EMB;
    const int NB = (n_nodes + BNODES - 1) / BNODES;   // 1172

    // ---- workspace carve (~90 MB) ----
    // fp16 state buffers each have one extra zero row at node index n_nodes.
    auto align_up = [](size_t x) { return (x + 1023) & ~(size_t)1023; };
    char* w = (char*)d_ws;
    int*   flag       = (int*)w; w += 1024;
    int*   bcount     = (int*)w; w += align_up((size_t)NB * sizeof(int));
    int*   bucketBase = (int*)w; w += align_up(((size_t)NB + 1) * sizeof(int));
    int*   bcur       = (int*)w; w += align_up((size_t)NB * sizeof(int));
    int*   offsets    = (int*)w; w += align_up(((size_t)n_nodes + 1) * sizeof(int));
    float* dis        = (float*)w; w += align_up((size_t)n_nodes * sizeof(float));
    int*   csr_rows   = (int*)w; w += align_up((size_t)n_edges * sizeof(int));
    size_t u_bytes = align_up(((size_t)n_elems + EMB) * sizeof(ushort));
    size_t p_bytes = align_up((size_t)n_edges * sizeof(uint));
    uint*   pairs = (uint*)w; w += p_bytes;
    ushort* z0    = (ushort*)w; w += u_bytes;
    ushort* z1    = (ushort*)w; w += u_bytes;
    ushort* z2    = (ushort*)w; w += u_bytes;

    // 0) setup: dtype detect + zero counters + zero dummy rows
    lgcn_setup_kernel<<<1, 256, 0, stream>>>(edge_index, flag, bcount, bcur,
                                             z0, z1, z2, NB, n_elems);

    // 1) bucket histogram -> scan -> staged scatter -> bucket CSR(+init)
    lgcn_bhist_kernel<<<(n_edges + 4095) / 4096, 256, 0, stream>>>(
        edge_index, flag, bcount, n_edges, n_nodes, NB);
    lgcn_bscan_kernel<<<1, 256, 0, stream>>>(bcount, bucketBase, offsets, NB, n_nodes);
    lgcn_bscatter3_kernel<<<(n_edges + CH - 1) / CH, STH, 0, stream>>>(
        edge_index, flag, bucketBase, bcur, pairs, n_edges, n_nodes, NB);
    lgcn_bcsr_kernel<<<NB, 256, 0, stream>>>(
        pairs, bucketBase, user_w, item_w, offsets, csr_rows, dis, z0,
        n_users * EMB, n_nodes);

    // 2) 3 pull layers: z0 -> z1 -> z2 -> (fused) out
    {
        const int BLK = 256;   // R14: 4 nodes/block — proven L2 locality
        long long n_thr = (long long)n_nodes * 64;
        int gW = (int)((n_thr + BLK - 1) / BLK);
        lgcn_gather_kernel<false><<<gW, BLK, 0, stream>>>(
            csr_rows, offsets, dis, z0, z1,
            nullptr, nullptr, nullptr, nullptr, 0, n_nodes);
        lgcn_gather_kernel<false><<<gW, BLK, 0, stream>>>(
            csr_rows, offsets, dis, z1, z2,
            nullptr, nullptr, nullptr, nullptr, 0, n_nodes);
        lgcn_gather_kernel<true><<<gW, BLK, 0, stream>>>(
            csr_rows, offsets, dis, z2, nullptr,
            z1, user_w, item_w, out, n_users * EMB, n_nodes);
    }
}